// Round 6
// baseline (574.491 us; speedup 1.0000x reference)
//
#include <hip/hip_runtime.h>

// CapsTimeModel forward, round 6: capsconv optimization.
//   - LDS union: grp aliases uloc4 (used in disjoint phases) -> 20.5 KB/block
//     -> 7 blocks/CU occupancy cap (was 4)
//   - weight repack cwp[kl][n][m][xd16]: 4x dwordx4 per item (was 16 scalar
//     stride-32 loads)
// Everything else identical to R5 (passing).

#define EPSLN 1e-5f

typedef short  short8 __attribute__((ext_vector_type(8)));
typedef __bf16 bf16x8 __attribute__((ext_vector_type(8)));
typedef float  f32x4  __attribute__((ext_vector_type(4)));

union Frag { short8 s; bf16x8 b; };

// ============================ repack kernels ============================
__global__ __launch_bounds__(256) void k_repack_bw(const float* __restrict__ bw,
                                                   float* __restrict__ bwT) {
    int i = blockIdx.x * 256 + threadIdx.x;       // 128*27 = 3456
    if (i >= 3456) return;
    int oc = i / 27, r = i % 27;
    bwT[r * 128 + oc] = bw[i];
}

__global__ __launch_bounds__(256) void k_repack_pcw(const float* __restrict__ pw,
                                                    __bf16* __restrict__ wbT) {
    int i = blockIdx.x * 256 + threadIdx.x;       // 512*1152 = 589824 exact
    int oc = i / 1152, r = i % 1152;
    int ic = r / 9, tap = r % 9;
    wbT[oc * 1152 + tap * 128 + ic] = (__bf16)pw[i];
}

__global__ __launch_bounds__(256) void k_repack_fw(const float* __restrict__ fw,
                                                   float* __restrict__ fwp) {
    int i = blockIdx.x * 256 + threadIdx.x;       // 250880 exact
    int m = i % 10;
    int d = (i / 10) & 3;
    int x = (i / 40) & 3;
    int n = i / 160;
    fwp[(m * 1568 + n) * 16 + x * 4 + d] = fw[i];
}

// cw (kl,n,xd,m) -> cwp[kl][n][m][xd]  (147456 elements)
__global__ __launch_bounds__(256) void k_repack_cw(const float* __restrict__ cw,
                                                   float* __restrict__ cwp) {
    int i = blockIdx.x * 256 + threadIdx.x;       // 576 blocks * 256 = 147456 exact
    int m  = i & 31;
    int xd = (i >> 5) & 15;
    int n  = (i >> 9) & 31;
    int kl = i >> 14;
    cwp[(((kl * 32 + n) * 32) + m) * 16 + xd] = cw[i];
}

// ==================== conv1: x -> c2p (NHWC bf16, padded) ====================
__global__ __launch_bounds__(256) void k_conv1(const float* __restrict__ x,
                                               const float* __restrict__ bwT,
                                               const float* __restrict__ bb,
                                               __bf16* __restrict__ c2p) {
    int gid = blockIdx.x * 256 + threadIdx.x;     // 64*32*32*128 = 8,388,608
    int oc = gid & 127;
    int p  = gid >> 7;
    int w = p & 31, h = (p >> 5) & 31, b = p >> 10;
    const float* xb = x + b * 3 * 64 * 64;
    float acc = bb[oc];
    #pragma unroll
    for (int ky = 0; ky < 3; ++ky) {
        int ih = 2 * h + ky - 1;
        if ((unsigned)ih >= 64u) continue;
        #pragma unroll
        for (int kx = 0; kx < 3; ++kx) {
            int iw = 2 * w + kx - 1;
            if ((unsigned)iw >= 64u) continue;
            #pragma unroll
            for (int ic = 0; ic < 3; ++ic)
                acc = fmaf(xb[(ic * 64 + ih) * 64 + iw],
                           bwT[(ic * 9 + ky * 3 + kx) * 128 + oc], acc);
        }
    }
    c2p[((b * 34 + h + 1) * 34 + (w + 1)) * 128 + oc] = (__bf16)fmaxf(acc, 0.f);
}

// ==================== conv2: MFMA GEMM + fused LN0 -> val ====================
__global__ __launch_bounds__(256) void k_conv2_mfma(const __bf16* __restrict__ c2p,
                                                    const __bf16* __restrict__ wbT,
                                                    const float* __restrict__ g,
                                                    const float* __restrict__ bt,
                                                    float* __restrict__ val) {
    __shared__ unsigned short sA[128 * 32];   // [row][k] bf16 bits, 8 KB
    __shared__ unsigned short sB[64 * 32];    // [oc][k]  bf16 bits, 4 KB

    const int t = threadIdx.x;
    const int mblk = blockIdx.x >> 3, nblk = blockIdx.x & 7;
    const int pbase = mblk * 128, ocbase = nblk * 64;
    const int b = pbase >> 8;

    const int r0 = t >> 2, r1 = r0 + 64;
    const int kc8 = (t & 3) * 8;
    const int oh0 = ((pbase + r0) >> 4) & 15, ow0 = (pbase + r0) & 15;
    const int oh1 = ((pbase + r1) >> 4) & 15, ow1 = (pbase + r1) & 15;

    const unsigned short* cb = (const unsigned short*)c2p + (size_t)b * 147968;
    const unsigned short* ws = (const unsigned short*)wbT
                               + (ocbase + (t >> 2)) * 1152 + kc8;

    const int lane = t & 63, wid = t >> 6;
    const int lo = lane & 15, hi = lane >> 4;

    f32x4 acc[2][4];
    #pragma unroll
    for (int fr = 0; fr < 2; ++fr)
        #pragma unroll
        for (int fc = 0; fc < 4; ++fc)
            acc[fr][fc] = (f32x4){0.f, 0.f, 0.f, 0.f};

    for (int ks = 0; ks < 36; ++ks) {
        const int tap = ks / 4;
        const int ic0 = (ks % 4) * 32;
        const int ty = tap / 3, tx = tap % 3;
        uint4 a0 = *(const uint4*)(cb + ((2 * oh0 + ty) * 34 + (2 * ow0 + tx)) * 128
                                      + ic0 + kc8);
        uint4 a1 = *(const uint4*)(cb + ((2 * oh1 + ty) * 34 + (2 * ow1 + tx)) * 128
                                      + ic0 + kc8);
        uint4 b0 = *(const uint4*)(ws + ks * 32);
        __syncthreads();
        *(uint4*)&sA[(unsigned)t * 8]         = a0;
        *(uint4*)&sA[((unsigned)t + 256) * 8] = a1;
        *(uint4*)&sB[(unsigned)t * 8]         = b0;
        __syncthreads();

        Frag af0, af1, bf[4];
        af0.s = *(const short8*)&sA[(wid * 32 + lo) * 32 + hi * 8];
        af1.s = *(const short8*)&sA[(wid * 32 + 16 + lo) * 32 + hi * 8];
        #pragma unroll
        for (int fc = 0; fc < 4; ++fc)
            bf[fc].s = *(const short8*)&sB[(fc * 16 + lo) * 32 + hi * 8];
        #pragma unroll
        for (int fc = 0; fc < 4; ++fc) {
            acc[0][fc] = __builtin_amdgcn_mfma_f32_16x16x32_bf16(
                af0.b, bf[fc].b, acc[0][fc], 0, 0, 0);
            acc[1][fc] = __builtin_amdgcn_mfma_f32_16x16x32_bf16(
                af1.b, bf[fc].b, acc[1][fc], 0, 0, 0);
        }
    }

    const float gv = g[lo], bv = bt[lo];
    #pragma unroll
    for (int fr = 0; fr < 2; ++fr) {
        #pragma unroll
        for (int fc = 0; fc < 4; ++fc) {
            const int n = (ocbase >> 4) + fc;
            #pragma unroll
            for (int j = 0; j < 4; ++j) {
                float v = acc[fr][fc][j];
                float s1 = v, s2 = v * v;
                #pragma unroll
                for (int off = 1; off < 16; off <<= 1) {
                    s1 += __shfl_xor(s1, off);
                    s2 += __shfl_xor(s2, off);
                }
                float mu  = s1 * (1.f / 16.f);
                float var = s2 * (1.f / 16.f) - mu * mu;
                float rs  = rsqrtf(var + EPSLN);
                float o   = (v - mu) * rs * gv + bv;
                int p  = pbase + wid * 32 + fr * 16 + hi * 4 + j;
                int oh = (p >> 4) & 15, ow = p & 15;
                val[(((b * 32 + n) * 16 + oh) * 16 + ow) * 16 + lo] = o;
            }
        }
    }
}

// ===================== caps conv step (+optional routing) + LN1 =====================
// LDS: uloc4 (stage) is aliased by grp (reduction) -- disjoint phases, barrier
// separated. Weights from cwp[kl][n][m][xd]: 4x dwordx4 per item per lane.
template <int ROUTING>
__global__ __launch_bounds__(256) void k_capsconv(const float* __restrict__ val,
                                                  const float* __restrict__ cwp,
                                                  const float* __restrict__ vprev,
                                                  const float* __restrict__ g,
                                                  const float* __restrict__ bt,
                                                  float* __restrict__ vout) {
    int b  = blockIdx.x / 49;
    int hw = blockIdx.x % 49;
    int h = hw / 7, w = hw % 7;

    __shared__ float4 uloc4[1152];        // 18432 B; aliased by grp after votes
    __shared__ float  nvfin[512];         // 2048 B
    float* grp = (float*)uloc4;           // [8][544] = 17408 B <= 18432

    for (int t = threadIdx.x; t < 1152; t += 256) {
        int f  = t & 3;
        int kl = (t >> 2) % 9;
        int n  = t / 36;
        int k = kl / 3, l = kl % 3;
        const float4* s = (const float4*)(val +
            (((b * 32 + n) * 16 + (2 * h + k)) * 16 + (2 * w + l)) * 16 + f * 4);
        uloc4[t] = *s;
    }

    int lane  = threadIdx.x & 31;   // m
    int grpid = threadIdx.x >> 5;   // 0..7

    float nvp[16];
    if (ROUTING) {
        const float* pv = vprev + (((b * 32 + lane) * 7 + h) * 7 + w) * 16;
        #pragma unroll
        for (int j = 0; j < 16; ++j) nvp[j] = pv[j];
    }
    float nvacc[16];
    #pragma unroll
    for (int j = 0; j < 16; ++j) nvacc[j] = 0.f;

    __syncthreads();

    for (int it = grpid; it < 288; it += 8) {     // it = n*9 + kl
        int n  = it / 9;
        int kl = it % 9;
        float u16[16];
        #pragma unroll
        for (int f = 0; f < 4; ++f) {
            float4 t4 = uloc4[it * 4 + f];
            u16[f * 4 + 0] = t4.x; u16[f * 4 + 1] = t4.y;
            u16[f * 4 + 2] = t4.z; u16[f * 4 + 3] = t4.w;
        }
        // weights: cwp[((kl*32+n)*32+m)*16 + x*4+d] -> 4 consecutive dwordx4
        const float4* wp4 = (const float4*)(cwp + (((kl * 32 + n) * 32) + lane) * 16);
        float4 w0 = wp4[0], w1 = wp4[1], w2 = wp4[2], w3 = wp4[3];  // [x][d0..3]
        float votes[16];
        #pragma unroll
        for (int a = 0; a < 4; ++a) {
            votes[a * 4 + 0] = u16[a * 4 + 0] * w0.x + u16[a * 4 + 1] * w1.x
                             + u16[a * 4 + 2] * w2.x + u16[a * 4 + 3] * w3.x;
            votes[a * 4 + 1] = u16[a * 4 + 0] * w0.y + u16[a * 4 + 1] * w1.y
                             + u16[a * 4 + 2] * w2.y + u16[a * 4 + 3] * w3.y;
            votes[a * 4 + 2] = u16[a * 4 + 0] * w0.z + u16[a * 4 + 1] * w1.z
                             + u16[a * 4 + 2] * w2.z + u16[a * 4 + 3] * w3.z;
            votes[a * 4 + 3] = u16[a * 4 + 0] * w0.w + u16[a * 4 + 1] * w1.w
                             + u16[a * 4 + 2] * w2.w + u16[a * 4 + 3] * w3.w;
        }
        float qv;
        if (ROUTING) {
            float qk = 0.f;
            #pragma unroll
            for (int j = 0; j < 16; ++j) qk = fmaf(votes[j], nvp[j], qk);
            qk *= 0.25f;                          // 1/sqrt(16)
            float mx = qk;
            #pragma unroll
            for (int off = 1; off < 32; off <<= 1) mx = fmaxf(mx, __shfl_xor(mx, off));
            float e = __expf(qk - mx);
            float s = e;
            #pragma unroll
            for (int off = 1; off < 32; off <<= 1) s += __shfl_xor(s, off);
            qv = e / s;
        } else {
            qv = 1.0f;
        }
        #pragma unroll
        for (int j = 0; j < 16; ++j) nvacc[j] = fmaf(qv, votes[j], nvacc[j]);
    }

    __syncthreads();   // all uloc4 reads complete before grp aliases it

    #pragma unroll
    for (int j = 0; j < 16; ++j) grp[grpid * 544 + lane * 17 + j] = nvacc[j];
    __syncthreads();

    {
        int o = threadIdx.x * 2;
        #pragma unroll
        for (int i = 0; i < 2; ++i, ++o) {
            int mm = o >> 4, j = o & 15;
            float s = 0.f;
            #pragma unroll
            for (int gg = 0; gg < 8; ++gg) s += grp[gg * 544 + mm * 17 + j];
            nvfin[o] = ROUTING ? s : s * (1.f / 32.f);
        }
    }
    __syncthreads();

    if (threadIdx.x < 32) {
        int m = threadIdx.x;
        float v16[16], mu = 0.f;
        #pragma unroll
        for (int j = 0; j < 16; ++j) { v16[j] = nvfin[m * 16 + j]; mu += v16[j]; }
        mu *= (1.f / 16.f);
        float var = 0.f;
        #pragma unroll
        for (int j = 0; j < 16; ++j) { float t = v16[j] - mu; var += t * t; }
        var *= (1.f / 16.f);
        float rs = rsqrtf(var + EPSLN);
        float o16[16];
        #pragma unroll
        for (int j = 0; j < 16; ++j) o16[j] = (v16[j] - mu) * rs * g[j] + bt[j];
        float4* dst = (float4*)(vout + (((b * 32 + m) * 7 + h) * 7 + w) * 16);
        dst[0] = make_float4(o16[0],  o16[1],  o16[2],  o16[3]);
        dst[1] = make_float4(o16[4],  o16[5],  o16[6],  o16[7]);
        dst[2] = make_float4(o16[8],  o16[9],  o16[10], o16[11]);
        dst[3] = make_float4(o16[12], o16[13], o16[14], o16[15]);
    }
}

// ===================== fc step1 + LN2: v2 -> p =====================
__global__ __launch_bounds__(256) void k_fc1(const float* __restrict__ fin,
                                             const float* __restrict__ fwp,
                                             const float* __restrict__ g,
                                             const float* __restrict__ bt,
                                             float* __restrict__ p) {
    int b = blockIdx.x / 10, m = blockIdx.x % 10;
    const float* fb = fin + b * 1568 * 16;
    const float* wb = fwp + m * 1568 * 16;
    float acc[16];
    #pragma unroll
    for (int j = 0; j < 16; ++j) acc[j] = 0.f;

    for (int n = threadIdx.x; n < 1568; n += 256) {
        const float4* u4 = (const float4*)(fb + n * 16);
        const float4* w4 = (const float4*)(wb + n * 16);
        float u16[16], w16[16];
        #pragma unroll
        for (int f = 0; f < 4; ++f) {
            float4 a = u4[f], bq = w4[f];
            u16[f * 4 + 0] = a.x;  u16[f * 4 + 1] = a.y;
            u16[f * 4 + 2] = a.z;  u16[f * 4 + 3] = a.w;
            w16[f * 4 + 0] = bq.x; w16[f * 4 + 1] = bq.y;
            w16[f * 4 + 2] = bq.z; w16[f * 4 + 3] = bq.w;
        }
        #pragma unroll
        for (int a = 0; a < 4; ++a)
            #pragma unroll
            for (int d = 0; d < 4; ++d) {
                float s = acc[a * 4 + d];
                #pragma unroll
                for (int x = 0; x < 4; ++x)
                    s = fmaf(u16[a * 4 + x], w16[x * 4 + d], s);
                acc[a * 4 + d] = s;
            }
    }
    #pragma unroll
    for (int j = 0; j < 16; ++j)
        #pragma unroll
        for (int off = 1; off < 64; off <<= 1)
            acc[j] += __shfl_xor(acc[j], off);

    __shared__ float red[4][16];
    int wid = threadIdx.x >> 6, ln = threadIdx.x & 63;
    if (ln == 0) {
        #pragma unroll
        for (int j = 0; j < 16; ++j) red[wid][j] = acc[j];
    }
    __syncthreads();
    if (threadIdx.x < 16) {
        int j = threadIdx.x;
        float s = (red[0][j] + red[1][j] + red[2][j] + red[3][j]) * 0.1f;
        float mu = s;
        #pragma unroll
        for (int off = 1; off < 16; off <<= 1) mu += __shfl_xor(mu, off);
        mu *= (1.f / 16.f);
        float t = s - mu;
        float var = t * t;
        #pragma unroll
        for (int off = 1; off < 16; off <<= 1) var += __shfl_xor(var, off);
        var *= (1.f / 16.f);
        float rs = rsqrtf(var + EPSLN);
        p[(b * 10 + m) * 16 + j] = t * rs * g[j] + bt[j];
    }
}

// ===================== fc routing + LN2: v2,p -> out =====================
__global__ __launch_bounds__(256) void k_fc2(const float* __restrict__ fin,
                                             const float* __restrict__ fw,
                                             const float* __restrict__ p,
                                             const float* __restrict__ g,
                                             const float* __restrict__ bt,
                                             float* __restrict__ out) {
    int b = blockIdx.x;
    int ad    = threadIdx.x & 15;
    int grpid = threadIdx.x >> 4;
    int a = ad >> 2, d = ad & 3;

    float pv[10];
    #pragma unroll
    for (int m = 0; m < 10; ++m) pv[m] = p[(b * 10 + m) * 16 + ad];

    float acc[10];
    #pragma unroll
    for (int m = 0; m < 10; ++m) acc[m] = 0.f;

    const float* fb = fin + b * 1568 * 16;
    for (int n = grpid; n < 1568; n += 16) {
        float4 u4 = *(const float4*)(fb + n * 16 + a * 4);
        const float* wb = fw + n * 160 + d * 10;
        float votes[10];
        #pragma unroll
        for (int m = 0; m < 10; ++m)
            votes[m] = u4.x * wb[m] + u4.y * wb[40 + m] +
                       u4.z * wb[80 + m] + u4.w * wb[120 + m];
        float qk[10];
        #pragma unroll
        for (int m = 0; m < 10; ++m) {
            float t = votes[m] * pv[m];
            #pragma unroll
            for (int off = 1; off < 16; off <<= 1) t += __shfl_xor(t, off);
            qk[m] = t * 0.25f;
        }
        float mx = qk[0];
        #pragma unroll
        for (int m = 1; m < 10; ++m) mx = fmaxf(mx, qk[m]);
        float e[10], s = 0.f;
        #pragma unroll
        for (int m = 0; m < 10; ++m) { e[m] = __expf(qk[m] - mx); s += e[m]; }
        float inv = 1.f / s;
        #pragma unroll
        for (int m = 0; m < 10; ++m) acc[m] = fmaf(e[m] * inv, votes[m], acc[m]);
    }

    __shared__ float red[16][16][10];
    #pragma unroll
    for (int m = 0; m < 10; ++m) red[grpid][ad][m] = acc[m];
    __syncthreads();

    if (threadIdx.x < 160) {
        int m = threadIdx.x / 16, j = threadIdx.x % 16;
        float s = 0.f;
        #pragma unroll
        for (int gg = 0; gg < 16; ++gg) s += red[gg][j][m];
        float mu = s;
        #pragma unroll
        for (int off = 1; off < 16; off <<= 1) mu += __shfl_xor(mu, off);
        mu *= (1.f / 16.f);
        float t = s - mu;
        float var = t * t;
        #pragma unroll
        for (int off = 1; off < 16; off <<= 1) var += __shfl_xor(var, off);
        var *= (1.f / 16.f);
        float rs = rsqrtf(var + EPSLN);
        out[(b * 10 + m) * 16 + j] = t * rs * g[j] + bt[j];
    }
}

// ============================ launch ============================
extern "C" void kernel_launch(void* const* d_in, const int* in_sizes, int n_in,
                              void* d_out, int out_size, void* d_ws, size_t ws_size,
                              hipStream_t stream) {
    const float* x    = (const float*)d_in[0];
    const float* bbw  = (const float*)d_in[1];
    const float* bbb  = (const float*)d_in[2];
    const float* pcw  = (const float*)d_in[3];
    const float* ln0g = (const float*)d_in[4];
    const float* ln0b = (const float*)d_in[5];
    const float* cwt  = (const float*)d_in[6];
    const float* ln1g = (const float*)d_in[7];
    const float* ln1b = (const float*)d_in[8];
    const float* fw   = (const float*)d_in[9];
    const float* ln2g = (const float*)d_in[10];
    const float* ln2b = (const float*)d_in[11];
    float* outp = (float*)d_out;

    float* ws = (float*)d_ws;
    __bf16* c2p = (__bf16*)ws;                 // [0, 4,734,976)
    __bf16* wbT = (__bf16*)(ws + 4734976);     // [4,734,976, 5,029,888)
    float*  bwT = ws + 5029888;                // [5,029,888, 5,033,344)
    float*  val = ws + 5033344;                // [5,033,344, 13,421,952)
    float*  v1  = ws + 13421952;               // [13,421,952, 15,027,584)
    float*  v2  = ws + 15027584;               // [15,027,584, 16,633,216)
    float*  fwp = ws + 16633216;               // [16,633,216, 16,884,096)
    float*  p   = ws + 16884096;               // [16,884,096, 16,894,336)
    float*  cwp = ws + 16894336;               // [16,894,336, 17,041,792) ~68.2 MB

    hipMemsetAsync(c2p, 0, (size_t)9469952 * 2, stream);
    k_repack_bw  <<<14,   256, 0, stream>>>(bbw, bwT);
    k_repack_pcw <<<2304, 256, 0, stream>>>(pcw, wbT);
    k_repack_fw  <<<980,  256, 0, stream>>>(fw, fwp);
    k_repack_cw  <<<576,  256, 0, stream>>>(cwt, cwp);
    k_conv1      <<<32768, 256, 0, stream>>>(x, bwT, bbb, c2p);
    k_conv2_mfma <<<1024, 256, 0, stream>>>(c2p, wbT, ln0g, ln0b, val);
    k_capsconv<0><<<3136, 256, 0, stream>>>(val, cwp, nullptr, ln1g, ln1b, v1);
    k_capsconv<1><<<3136, 256, 0, stream>>>(val, cwp, v1, ln1g, ln1b, v2);
    k_fc1        <<<640, 256, 0, stream>>>(v2, fwp, ln2g, ln2b, p);
    k_fc2        <<<64, 256, 0, stream>>>(v2, fw, p, ln2g, ln2b, outp);
}

// Round 7
// 503.430 us; speedup vs baseline: 1.1412x; 1.1412x over previous
//
#include <hip/hip_runtime.h>

// CapsTimeModel forward, round 7: fused caps routing.
//   - k_capsfused: both routing passes in ONE kernel, 2 sites (b, b+32) per
//     block -> weights read once per item per block (L2 traffic halved),
//     val staged once, v1 kept in LDS, one launch.
//   - capsconv loop body = R5's (16 coalesced scalar weight loads) -- R6's
//     dwordx4 repack regressed (VALUBusy 61->54) and is reverted.
// conv1/conv2/fc1/fc2 identical to R5/R6 (passing).

#define EPSLN 1e-5f

typedef short  short8 __attribute__((ext_vector_type(8)));
typedef __bf16 bf16x8 __attribute__((ext_vector_type(8)));
typedef float  f32x4  __attribute__((ext_vector_type(4)));

union Frag { short8 s; bf16x8 b; };

// ============================ repack kernels ============================
__global__ __launch_bounds__(256) void k_repack_bw(const float* __restrict__ bw,
                                                   float* __restrict__ bwT) {
    int i = blockIdx.x * 256 + threadIdx.x;       // 128*27 = 3456
    if (i >= 3456) return;
    int oc = i / 27, r = i % 27;
    bwT[r * 128 + oc] = bw[i];
}

__global__ __launch_bounds__(256) void k_repack_pcw(const float* __restrict__ pw,
                                                    __bf16* __restrict__ wbT) {
    int i = blockIdx.x * 256 + threadIdx.x;       // 512*1152 = 589824 exact
    int oc = i / 1152, r = i % 1152;
    int ic = r / 9, tap = r % 9;
    wbT[oc * 1152 + tap * 128 + ic] = (__bf16)pw[i];
}

__global__ __launch_bounds__(256) void k_repack_fw(const float* __restrict__ fw,
                                                   float* __restrict__ fwp) {
    int i = blockIdx.x * 256 + threadIdx.x;       // 250880 exact
    int m = i % 10;
    int d = (i / 10) & 3;
    int x = (i / 40) & 3;
    int n = i / 160;
    fwp[(m * 1568 + n) * 16 + x * 4 + d] = fw[i];
}

// ==================== conv1: x -> c2p (NHWC bf16, padded) ====================
__global__ __launch_bounds__(256) void k_conv1(const float* __restrict__ x,
                                               const float* __restrict__ bwT,
                                               const float* __restrict__ bb,
                                               __bf16* __restrict__ c2p) {
    int gid = blockIdx.x * 256 + threadIdx.x;     // 64*32*32*128 = 8,388,608
    int oc = gid & 127;
    int p  = gid >> 7;
    int w = p & 31, h = (p >> 5) & 31, b = p >> 10;
    const float* xb = x + b * 3 * 64 * 64;
    float acc = bb[oc];
    #pragma unroll
    for (int ky = 0; ky < 3; ++ky) {
        int ih = 2 * h + ky - 1;
        if ((unsigned)ih >= 64u) continue;
        #pragma unroll
        for (int kx = 0; kx < 3; ++kx) {
            int iw = 2 * w + kx - 1;
            if ((unsigned)iw >= 64u) continue;
            #pragma unroll
            for (int ic = 0; ic < 3; ++ic)
                acc = fmaf(xb[(ic * 64 + ih) * 64 + iw],
                           bwT[(ic * 9 + ky * 3 + kx) * 128 + oc], acc);
        }
    }
    c2p[((b * 34 + h + 1) * 34 + (w + 1)) * 128 + oc] = (__bf16)fmaxf(acc, 0.f);
}

// ==================== conv2: MFMA GEMM + fused LN0 -> val ====================
__global__ __launch_bounds__(256) void k_conv2_mfma(const __bf16* __restrict__ c2p,
                                                    const __bf16* __restrict__ wbT,
                                                    const float* __restrict__ g,
                                                    const float* __restrict__ bt,
                                                    float* __restrict__ val) {
    __shared__ unsigned short sA[128 * 32];
    __shared__ unsigned short sB[64 * 32];

    const int t = threadIdx.x;
    const int mblk = blockIdx.x >> 3, nblk = blockIdx.x & 7;
    const int pbase = mblk * 128, ocbase = nblk * 64;
    const int b = pbase >> 8;

    const int r0 = t >> 2, r1 = r0 + 64;
    const int kc8 = (t & 3) * 8;
    const int oh0 = ((pbase + r0) >> 4) & 15, ow0 = (pbase + r0) & 15;
    const int oh1 = ((pbase + r1) >> 4) & 15, ow1 = (pbase + r1) & 15;

    const unsigned short* cb = (const unsigned short*)c2p + (size_t)b * 147968;
    const unsigned short* ws = (const unsigned short*)wbT
                               + (ocbase + (t >> 2)) * 1152 + kc8;

    const int lane = t & 63, wid = t >> 6;
    const int lo = lane & 15, hi = lane >> 4;

    f32x4 acc[2][4];
    #pragma unroll
    for (int fr = 0; fr < 2; ++fr)
        #pragma unroll
        for (int fc = 0; fc < 4; ++fc)
            acc[fr][fc] = (f32x4){0.f, 0.f, 0.f, 0.f};

    for (int ks = 0; ks < 36; ++ks) {
        const int tap = ks / 4;
        const int ic0 = (ks % 4) * 32;
        const int ty = tap / 3, tx = tap % 3;
        uint4 a0 = *(const uint4*)(cb + ((2 * oh0 + ty) * 34 + (2 * ow0 + tx)) * 128
                                      + ic0 + kc8);
        uint4 a1 = *(const uint4*)(cb + ((2 * oh1 + ty) * 34 + (2 * ow1 + tx)) * 128
                                      + ic0 + kc8);
        uint4 b0 = *(const uint4*)(ws + ks * 32);
        __syncthreads();
        *(uint4*)&sA[(unsigned)t * 8]         = a0;
        *(uint4*)&sA[((unsigned)t + 256) * 8] = a1;
        *(uint4*)&sB[(unsigned)t * 8]         = b0;
        __syncthreads();

        Frag af0, af1, bf[4];
        af0.s = *(const short8*)&sA[(wid * 32 + lo) * 32 + hi * 8];
        af1.s = *(const short8*)&sA[(wid * 32 + 16 + lo) * 32 + hi * 8];
        #pragma unroll
        for (int fc = 0; fc < 4; ++fc)
            bf[fc].s = *(const short8*)&sB[(fc * 16 + lo) * 32 + hi * 8];
        #pragma unroll
        for (int fc = 0; fc < 4; ++fc) {
            acc[0][fc] = __builtin_amdgcn_mfma_f32_16x16x32_bf16(
                af0.b, bf[fc].b, acc[0][fc], 0, 0, 0);
            acc[1][fc] = __builtin_amdgcn_mfma_f32_16x16x32_bf16(
                af1.b, bf[fc].b, acc[1][fc], 0, 0, 0);
        }
    }

    const float gv = g[lo], bv = bt[lo];
    #pragma unroll
    for (int fr = 0; fr < 2; ++fr) {
        #pragma unroll
        for (int fc = 0; fc < 4; ++fc) {
            const int n = (ocbase >> 4) + fc;
            #pragma unroll
            for (int j = 0; j < 4; ++j) {
                float v = acc[fr][fc][j];
                float s1 = v, s2 = v * v;
                #pragma unroll
                for (int off = 1; off < 16; off <<= 1) {
                    s1 += __shfl_xor(s1, off);
                    s2 += __shfl_xor(s2, off);
                }
                float mu  = s1 * (1.f / 16.f);
                float var = s2 * (1.f / 16.f) - mu * mu;
                float rs  = rsqrtf(var + EPSLN);
                float o   = (v - mu) * rs * gv + bv;
                int p  = pbase + wid * 32 + fr * 16 + hi * 4 + j;
                int oh = (p >> 4) & 15, ow = p & 15;
                val[(((b * 32 + n) * 16 + oh) * 16 + ow) * 16 + lo] = o;
            }
        }
    }
}

// ===================== fused caps routing (pass1 + pass2) + LN1 =====================
// Block = 2 sites: (b=bb, h, w) and (b=bb+32, h, w). 8 groups of 32 lanes
// (lane = m); group walks items it = n*9+kl stepping 8. Weights loaded once
// per item per group, applied to both sites. v1 lives in LDS between passes.
__global__ __launch_bounds__(256) void k_capsfused(const float* __restrict__ val,
                                                   const float* __restrict__ cw,
                                                   const float* __restrict__ g,
                                                   const float* __restrict__ bt,
                                                   float* __restrict__ vout) {
    int bb = blockIdx.x / 49;
    int hw = blockIdx.x % 49;
    int h = hw / 7, w = hw % 7;

    __shared__ float4 uloc4[2][1152];   // 36864 B  u tiles for both sites
    __shared__ float  wred[4 * 544];    //  8704 B  cross-wave reduce [wid][m][17]
    __shared__ float  v1s[2][512];      //  4096 B  v1 (LN'd) / nv2 scratch

    // stage unfolded val for both sites
    for (int t = threadIdx.x; t < 2304; t += 256) {
        int s  = t >= 1152;
        int tt = t - s * 1152;
        int f  = tt & 3;
        int kl = (tt >> 2) % 9;
        int n  = tt / 36;
        int k = kl / 3, l = kl % 3;
        int b = bb + s * 32;
        uloc4[s][tt] = *(const float4*)(val +
            (((b * 32 + n) * 16 + (2 * h + k)) * 16 + (2 * w + l)) * 16 + f * 4);
    }

    const int lane  = threadIdx.x & 31;          // m
    const int grpid = threadIdx.x >> 5;          // 0..7
    const int wid   = threadIdx.x >> 6;          // 0..3
    const bool half0 = (threadIdx.x & 32) == 0;

    float nvacc[2][16];
    #pragma unroll
    for (int s = 0; s < 2; ++s)
        #pragma unroll
        for (int j = 0; j < 16; ++j) nvacc[s][j] = 0.f;

    __syncthreads();

    // ---------------- pass 1: nv1 = sum(votes)/32 ----------------
    for (int it = grpid; it < 288; it += 8) {
        int n  = it / 9;
        int kl = it % 9;
        const float* cwb = cw + (kl * 32 + n) * 512 + lane;
        float cwv[16];
        #pragma unroll
        for (int xd = 0; xd < 16; ++xd) cwv[xd] = cwb[xd * 32];
        #pragma unroll
        for (int s = 0; s < 2; ++s) {
            float u16[16];
            #pragma unroll
            for (int f = 0; f < 4; ++f) {
                float4 t4 = uloc4[s][it * 4 + f];
                u16[f * 4 + 0] = t4.x; u16[f * 4 + 1] = t4.y;
                u16[f * 4 + 2] = t4.z; u16[f * 4 + 3] = t4.w;
            }
            #pragma unroll
            for (int a = 0; a < 4; ++a)
                #pragma unroll
                for (int d = 0; d < 4; ++d) {
                    float v = 0.f;
                    #pragma unroll
                    for (int x = 0; x < 4; ++x)
                        v = fmaf(u16[a * 4 + x], cwv[x * 4 + d], v);
                    nvacc[s][a * 4 + d] += v;
                }
        }
    }

    // reduce: half-waves -> waves(LDS) -> nv1 -> LN -> v1s
    #pragma unroll
    for (int s = 0; s < 2; ++s)
        #pragma unroll
        for (int j = 0; j < 16; ++j)
            nvacc[s][j] += __shfl_xor(nvacc[s][j], 32);
    #pragma unroll
    for (int s = 0; s < 2; ++s) {
        __syncthreads();
        if (half0) {
            #pragma unroll
            for (int j = 0; j < 16; ++j) wred[wid * 544 + lane * 17 + j] = nvacc[s][j];
        }
        __syncthreads();
        for (int o = threadIdx.x; o < 512; o += 256) {
            int mm = o >> 4, j = o & 15;
            float sum = wred[0 * 544 + mm * 17 + j] + wred[1 * 544 + mm * 17 + j]
                      + wred[2 * 544 + mm * 17 + j] + wred[3 * 544 + mm * 17 + j];
            v1s[s][o] = sum * (1.f / 32.f);
        }
    }
    __syncthreads();
    if (threadIdx.x < 64) {       // LN per (s, m)
        int s = threadIdx.x >> 5, m = threadIdx.x & 31;
        float v16[16], mu = 0.f;
        #pragma unroll
        for (int j = 0; j < 16; ++j) { v16[j] = v1s[s][m * 16 + j]; mu += v16[j]; }
        mu *= (1.f / 16.f);
        float var = 0.f;
        #pragma unroll
        for (int j = 0; j < 16; ++j) { float t = v16[j] - mu; var += t * t; }
        var *= (1.f / 16.f);
        float rs = rsqrtf(var + EPSLN);
        #pragma unroll
        for (int j = 0; j < 16; ++j)
            v1s[s][m * 16 + j] = (v16[j] - mu) * rs * g[j] + bt[j];
    }
    __syncthreads();

    // ---------------- pass 2: routed ----------------
    float nvp[2][16];
    #pragma unroll
    for (int s = 0; s < 2; ++s)
        #pragma unroll
        for (int j = 0; j < 16; ++j) nvp[s][j] = v1s[s][lane * 16 + j];

    #pragma unroll
    for (int s = 0; s < 2; ++s)
        #pragma unroll
        for (int j = 0; j < 16; ++j) nvacc[s][j] = 0.f;

    for (int it = grpid; it < 288; it += 8) {
        int n  = it / 9;
        int kl = it % 9;
        const float* cwb = cw + (kl * 32 + n) * 512 + lane;
        float cwv[16];
        #pragma unroll
        for (int xd = 0; xd < 16; ++xd) cwv[xd] = cwb[xd * 32];
        #pragma unroll
        for (int s = 0; s < 2; ++s) {
            float u16[16];
            #pragma unroll
            for (int f = 0; f < 4; ++f) {
                float4 t4 = uloc4[s][it * 4 + f];
                u16[f * 4 + 0] = t4.x; u16[f * 4 + 1] = t4.y;
                u16[f * 4 + 2] = t4.z; u16[f * 4 + 3] = t4.w;
            }
            float votes[16];
            #pragma unroll
            for (int a = 0; a < 4; ++a)
                #pragma unroll
                for (int d = 0; d < 4; ++d) {
                    float v = 0.f;
                    #pragma unroll
                    for (int x = 0; x < 4; ++x)
                        v = fmaf(u16[a * 4 + x], cwv[x * 4 + d], v);
                    votes[a * 4 + d] = v;
                }
            float qk = 0.f;
            #pragma unroll
            for (int j = 0; j < 16; ++j) qk = fmaf(votes[j], nvp[s][j], qk);
            qk *= 0.25f;                          // 1/sqrt(16)
            float mx = qk;
            #pragma unroll
            for (int off = 1; off < 32; off <<= 1) mx = fmaxf(mx, __shfl_xor(mx, off));
            float e = __expf(qk - mx);
            float sm = e;
            #pragma unroll
            for (int off = 1; off < 32; off <<= 1) sm += __shfl_xor(sm, off);
            float qv = e / sm;
            #pragma unroll
            for (int j = 0; j < 16; ++j) nvacc[s][j] = fmaf(qv, votes[j], nvacc[s][j]);
        }
    }

    // reduce pass 2 -> nv2 -> LN -> global
    #pragma unroll
    for (int s = 0; s < 2; ++s)
        #pragma unroll
        for (int j = 0; j < 16; ++j)
            nvacc[s][j] += __shfl_xor(nvacc[s][j], 32);
    #pragma unroll
    for (int s = 0; s < 2; ++s) {
        __syncthreads();
        if (half0) {
            #pragma unroll
            for (int j = 0; j < 16; ++j) wred[wid * 544 + lane * 17 + j] = nvacc[s][j];
        }
        __syncthreads();
        for (int o = threadIdx.x; o < 512; o += 256) {
            int mm = o >> 4, j = o & 15;
            float sum = wred[0 * 544 + mm * 17 + j] + wred[1 * 544 + mm * 17 + j]
                      + wred[2 * 544 + mm * 17 + j] + wred[3 * 544 + mm * 17 + j];
            v1s[s][o] = sum;
        }
    }
    __syncthreads();
    if (threadIdx.x < 64) {
        int s = threadIdx.x >> 5, m = threadIdx.x & 31;
        int b = bb + s * 32;
        float v16[16], mu = 0.f;
        #pragma unroll
        for (int j = 0; j < 16; ++j) { v16[j] = v1s[s][m * 16 + j]; mu += v16[j]; }
        mu *= (1.f / 16.f);
        float var = 0.f;
        #pragma unroll
        for (int j = 0; j < 16; ++j) { float t = v16[j] - mu; var += t * t; }
        var *= (1.f / 16.f);
        float rs = rsqrtf(var + EPSLN);
        float o16[16];
        #pragma unroll
        for (int j = 0; j < 16; ++j) o16[j] = (v16[j] - mu) * rs * g[j] + bt[j];
        float4* dst = (float4*)(vout + (((b * 32 + m) * 7 + h) * 7 + w) * 16);
        dst[0] = make_float4(o16[0],  o16[1],  o16[2],  o16[3]);
        dst[1] = make_float4(o16[4],  o16[5],  o16[6],  o16[7]);
        dst[2] = make_float4(o16[8],  o16[9],  o16[10], o16[11]);
        dst[3] = make_float4(o16[12], o16[13], o16[14], o16[15]);
    }
}

// ===================== fc step1 + LN2: v2 -> p =====================
__global__ __launch_bounds__(256) void k_fc1(const float* __restrict__ fin,
                                             const float* __restrict__ fwp,
                                             const float* __restrict__ g,
                                             const float* __restrict__ bt,
                                             float* __restrict__ p) {
    int b = blockIdx.x / 10, m = blockIdx.x % 10;
    const float* fb = fin + b * 1568 * 16;
    const float* wb = fwp + m * 1568 * 16;
    float acc[16];
    #pragma unroll
    for (int j = 0; j < 16; ++j) acc[j] = 0.f;

    for (int n = threadIdx.x; n < 1568; n += 256) {
        const float4* u4 = (const float4*)(fb + n * 16);
        const float4* w4 = (const float4*)(wb + n * 16);
        float u16[16], w16[16];
        #pragma unroll
        for (int f = 0; f < 4; ++f) {
            float4 a = u4[f], bq = w4[f];
            u16[f * 4 + 0] = a.x;  u16[f * 4 + 1] = a.y;
            u16[f * 4 + 2] = a.z;  u16[f * 4 + 3] = a.w;
            w16[f * 4 + 0] = bq.x; w16[f * 4 + 1] = bq.y;
            w16[f * 4 + 2] = bq.z; w16[f * 4 + 3] = bq.w;
        }
        #pragma unroll
        for (int a = 0; a < 4; ++a)
            #pragma unroll
            for (int d = 0; d < 4; ++d) {
                float s = acc[a * 4 + d];
                #pragma unroll
                for (int x = 0; x < 4; ++x)
                    s = fmaf(u16[a * 4 + x], w16[x * 4 + d], s);
                acc[a * 4 + d] = s;
            }
    }
    #pragma unroll
    for (int j = 0; j < 16; ++j)
        #pragma unroll
        for (int off = 1; off < 64; off <<= 1)
            acc[j] += __shfl_xor(acc[j], off);

    __shared__ float red[4][16];
    int wid = threadIdx.x >> 6, ln = threadIdx.x & 63;
    if (ln == 0) {
        #pragma unroll
        for (int j = 0; j < 16; ++j) red[wid][j] = acc[j];
    }
    __syncthreads();
    if (threadIdx.x < 16) {
        int j = threadIdx.x;
        float s = (red[0][j] + red[1][j] + red[2][j] + red[3][j]) * 0.1f;
        float mu = s;
        #pragma unroll
        for (int off = 1; off < 16; off <<= 1) mu += __shfl_xor(mu, off);
        mu *= (1.f / 16.f);
        float t = s - mu;
        float var = t * t;
        #pragma unroll
        for (int off = 1; off < 16; off <<= 1) var += __shfl_xor(var, off);
        var *= (1.f / 16.f);
        float rs = rsqrtf(var + EPSLN);
        p[(b * 10 + m) * 16 + j] = t * rs * g[j] + bt[j];
    }
}

// ===================== fc routing + LN2: v2,p -> out =====================
__global__ __launch_bounds__(256) void k_fc2(const float* __restrict__ fin,
                                             const float* __restrict__ fw,
                                             const float* __restrict__ p,
                                             const float* __restrict__ g,
                                             const float* __restrict__ bt,
                                             float* __restrict__ out) {
    int b = blockIdx.x;
    int ad    = threadIdx.x & 15;
    int grpid = threadIdx.x >> 4;
    int a = ad >> 2, d = ad & 3;

    float pv[10];
    #pragma unroll
    for (int m = 0; m < 10; ++m) pv[m] = p[(b * 10 + m) * 16 + ad];

    float acc[10];
    #pragma unroll
    for (int m = 0; m < 10; ++m) acc[m] = 0.f;

    const float* fb = fin + b * 1568 * 16;
    for (int n = grpid; n < 1568; n += 16) {
        float4 u4 = *(const float4*)(fb + n * 16 + a * 4);
        const float* wb = fw + n * 160 + d * 10;
        float votes[10];
        #pragma unroll
        for (int m = 0; m < 10; ++m)
            votes[m] = u4.x * wb[m] + u4.y * wb[40 + m] +
                       u4.z * wb[80 + m] + u4.w * wb[120 + m];
        float qk[10];
        #pragma unroll
        for (int m = 0; m < 10; ++m) {
            float t = votes[m] * pv[m];
            #pragma unroll
            for (int off = 1; off < 16; off <<= 1) t += __shfl_xor(t, off);
            qk[m] = t * 0.25f;
        }
        float mx = qk[0];
        #pragma unroll
        for (int m = 1; m < 10; ++m) mx = fmaxf(mx, qk[m]);
        float e[10], s = 0.f;
        #pragma unroll
        for (int m = 0; m < 10; ++m) { e[m] = __expf(qk[m] - mx); s += e[m]; }
        float inv = 1.f / s;
        #pragma unroll
        for (int m = 0; m < 10; ++m) acc[m] = fmaf(e[m] * inv, votes[m], acc[m]);
    }

    __shared__ float red[16][16][10];
    #pragma unroll
    for (int m = 0; m < 10; ++m) red[grpid][ad][m] = acc[m];
    __syncthreads();

    if (threadIdx.x < 160) {
        int m = threadIdx.x / 16, j = threadIdx.x % 16;
        float s = 0.f;
        #pragma unroll
        for (int gg = 0; gg < 16; ++gg) s += red[gg][j][m];
        float mu = s;
        #pragma unroll
        for (int off = 1; off < 16; off <<= 1) mu += __shfl_xor(mu, off);
        mu *= (1.f / 16.f);
        float t = s - mu;
        float var = t * t;
        #pragma unroll
        for (int off = 1; off < 16; off <<= 1) var += __shfl_xor(var, off);
        var *= (1.f / 16.f);
        float rs = rsqrtf(var + EPSLN);
        out[(b * 10 + m) * 16 + j] = t * rs * g[j] + bt[j];
    }
}

// ============================ launch ============================
extern "C" void kernel_launch(void* const* d_in, const int* in_sizes, int n_in,
                              void* d_out, int out_size, void* d_ws, size_t ws_size,
                              hipStream_t stream) {
    const float* x    = (const float*)d_in[0];
    const float* bbw  = (const float*)d_in[1];
    const float* bbb  = (const float*)d_in[2];
    const float* pcw  = (const float*)d_in[3];
    const float* ln0g = (const float*)d_in[4];
    const float* ln0b = (const float*)d_in[5];
    const float* cwt  = (const float*)d_in[6];
    const float* ln1g = (const float*)d_in[7];
    const float* ln1b = (const float*)d_in[8];
    const float* fw   = (const float*)d_in[9];
    const float* ln2g = (const float*)d_in[10];
    const float* ln2b = (const float*)d_in[11];
    float* outp = (float*)d_out;

    float* ws = (float*)d_ws;
    __bf16* c2p = (__bf16*)ws;                 // [0, 4,734,976)
    __bf16* wbT = (__bf16*)(ws + 4734976);     // [4,734,976, 5,029,888)
    float*  bwT = ws + 5029888;                // [5,029,888, 5,033,344)
    float*  val = ws + 5033344;                // [5,033,344, 13,421,952)
    float*  v2  = ws + 15027584;               // [15,027,584, 16,633,216)
    float*  fwp = ws + 16633216;               // [16,633,216, 16,884,096)
    float*  p   = ws + 16884096;               // [16,884,096, 16,894,336)

    hipMemsetAsync(c2p, 0, (size_t)9469952 * 2, stream);
    k_repack_bw  <<<14,   256, 0, stream>>>(bbw, bwT);
    k_repack_pcw <<<2304, 256, 0, stream>>>(pcw, wbT);
    k_repack_fw  <<<980,  256, 0, stream>>>(fw, fwp);
    k_conv1      <<<32768, 256, 0, stream>>>(x, bwT, bbb, c2p);
    k_conv2_mfma <<<1024, 256, 0, stream>>>(c2p, wbT, ln0g, ln0b, val);
    k_capsfused  <<<1568, 256, 0, stream>>>(val, cwt, ln1g, ln1b, v2);
    k_fc1        <<<640, 256, 0, stream>>>(v2, fwp, ln2g, ln2b, p);
    k_fc2        <<<64, 256, 0, stream>>>(v2, fw, p, ln2g, ln2b, outp);
}

// Round 8
// 466.358 us; speedup vs baseline: 1.2319x; 1.0795x over previous
//
#include <hip/hip_runtime.h>

// CapsTimeModel forward, round 8: fused caps routing, occupancy + DS diet.
//   - uloc staged as bf16 (18.4KB vs 36.9KB) -> block LDS 31.2KB -> 5 blocks/CU
//   - softmax without max-subtract (shift-invariant; clamp +-30 for safety):
//     5 cross-lane ops per site-item instead of 10
//   - pass 1 accumulates votes directly (no temp)
// conv1/conv2/fc1/fc2 identical to R5-R7 (passing).

#define EPSLN 1e-5f

typedef short  short8 __attribute__((ext_vector_type(8)));
typedef __bf16 bf16x8 __attribute__((ext_vector_type(8)));
typedef float  f32x4  __attribute__((ext_vector_type(4)));

union Frag { short8 s; bf16x8 b; };

__device__ __forceinline__ uint4 pack_bf16_8(float4 a, float4 b) {
    union { __bf16 h[8]; uint4 u; } r;
    r.h[0] = (__bf16)a.x; r.h[1] = (__bf16)a.y;
    r.h[2] = (__bf16)a.z; r.h[3] = (__bf16)a.w;
    r.h[4] = (__bf16)b.x; r.h[5] = (__bf16)b.y;
    r.h[6] = (__bf16)b.z; r.h[7] = (__bf16)b.w;
    return r.u;
}

// ============================ repack kernels ============================
__global__ __launch_bounds__(256) void k_repack_bw(const float* __restrict__ bw,
                                                   float* __restrict__ bwT) {
    int i = blockIdx.x * 256 + threadIdx.x;       // 128*27 = 3456
    if (i >= 3456) return;
    int oc = i / 27, r = i % 27;
    bwT[r * 128 + oc] = bw[i];
}

__global__ __launch_bounds__(256) void k_repack_pcw(const float* __restrict__ pw,
                                                    __bf16* __restrict__ wbT) {
    int i = blockIdx.x * 256 + threadIdx.x;       // 512*1152 = 589824 exact
    int oc = i / 1152, r = i % 1152;
    int ic = r / 9, tap = r % 9;
    wbT[oc * 1152 + tap * 128 + ic] = (__bf16)pw[i];
}

__global__ __launch_bounds__(256) void k_repack_fw(const float* __restrict__ fw,
                                                   float* __restrict__ fwp) {
    int i = blockIdx.x * 256 + threadIdx.x;       // 250880 exact
    int m = i % 10;
    int d = (i / 10) & 3;
    int x = (i / 40) & 3;
    int n = i / 160;
    fwp[(m * 1568 + n) * 16 + x * 4 + d] = fw[i];
}

// ==================== conv1: x -> c2p (NHWC bf16, padded) ====================
__global__ __launch_bounds__(256) void k_conv1(const float* __restrict__ x,
                                               const float* __restrict__ bwT,
                                               const float* __restrict__ bb,
                                               __bf16* __restrict__ c2p) {
    int gid = blockIdx.x * 256 + threadIdx.x;     // 64*32*32*128 = 8,388,608
    int oc = gid & 127;
    int p  = gid >> 7;
    int w = p & 31, h = (p >> 5) & 31, b = p >> 10;
    const float* xb = x + b * 3 * 64 * 64;
    float acc = bb[oc];
    #pragma unroll
    for (int ky = 0; ky < 3; ++ky) {
        int ih = 2 * h + ky - 1;
        if ((unsigned)ih >= 64u) continue;
        #pragma unroll
        for (int kx = 0; kx < 3; ++kx) {
            int iw = 2 * w + kx - 1;
            if ((unsigned)iw >= 64u) continue;
            #pragma unroll
            for (int ic = 0; ic < 3; ++ic)
                acc = fmaf(xb[(ic * 64 + ih) * 64 + iw],
                           bwT[(ic * 9 + ky * 3 + kx) * 128 + oc], acc);
        }
    }
    c2p[((b * 34 + h + 1) * 34 + (w + 1)) * 128 + oc] = (__bf16)fmaxf(acc, 0.f);
}

// ==================== conv2: MFMA GEMM + fused LN0 -> val ====================
__global__ __launch_bounds__(256) void k_conv2_mfma(const __bf16* __restrict__ c2p,
                                                    const __bf16* __restrict__ wbT,
                                                    const float* __restrict__ g,
                                                    const float* __restrict__ bt,
                                                    float* __restrict__ val) {
    __shared__ unsigned short sA[128 * 32];
    __shared__ unsigned short sB[64 * 32];

    const int t = threadIdx.x;
    const int mblk = blockIdx.x >> 3, nblk = blockIdx.x & 7;
    const int pbase = mblk * 128, ocbase = nblk * 64;
    const int b = pbase >> 8;

    const int r0 = t >> 2, r1 = r0 + 64;
    const int kc8 = (t & 3) * 8;
    const int oh0 = ((pbase + r0) >> 4) & 15, ow0 = (pbase + r0) & 15;
    const int oh1 = ((pbase + r1) >> 4) & 15, ow1 = (pbase + r1) & 15;

    const unsigned short* cb = (const unsigned short*)c2p + (size_t)b * 147968;
    const unsigned short* ws = (const unsigned short*)wbT
                               + (ocbase + (t >> 2)) * 1152 + kc8;

    const int lane = t & 63, wid = t >> 6;
    const int lo = lane & 15, hi = lane >> 4;

    f32x4 acc[2][4];
    #pragma unroll
    for (int fr = 0; fr < 2; ++fr)
        #pragma unroll
        for (int fc = 0; fc < 4; ++fc)
            acc[fr][fc] = (f32x4){0.f, 0.f, 0.f, 0.f};

    for (int ks = 0; ks < 36; ++ks) {
        const int tap = ks / 4;
        const int ic0 = (ks % 4) * 32;
        const int ty = tap / 3, tx = tap % 3;
        uint4 a0 = *(const uint4*)(cb + ((2 * oh0 + ty) * 34 + (2 * ow0 + tx)) * 128
                                      + ic0 + kc8);
        uint4 a1 = *(const uint4*)(cb + ((2 * oh1 + ty) * 34 + (2 * ow1 + tx)) * 128
                                      + ic0 + kc8);
        uint4 b0 = *(const uint4*)(ws + ks * 32);
        __syncthreads();
        *(uint4*)&sA[(unsigned)t * 8]         = a0;
        *(uint4*)&sA[((unsigned)t + 256) * 8] = a1;
        *(uint4*)&sB[(unsigned)t * 8]         = b0;
        __syncthreads();

        Frag af0, af1, bf[4];
        af0.s = *(const short8*)&sA[(wid * 32 + lo) * 32 + hi * 8];
        af1.s = *(const short8*)&sA[(wid * 32 + 16 + lo) * 32 + hi * 8];
        #pragma unroll
        for (int fc = 0; fc < 4; ++fc)
            bf[fc].s = *(const short8*)&sB[(fc * 16 + lo) * 32 + hi * 8];
        #pragma unroll
        for (int fc = 0; fc < 4; ++fc) {
            acc[0][fc] = __builtin_amdgcn_mfma_f32_16x16x32_bf16(
                af0.b, bf[fc].b, acc[0][fc], 0, 0, 0);
            acc[1][fc] = __builtin_amdgcn_mfma_f32_16x16x32_bf16(
                af1.b, bf[fc].b, acc[1][fc], 0, 0, 0);
        }
    }

    const float gv = g[lo], bv = bt[lo];
    #pragma unroll
    for (int fr = 0; fr < 2; ++fr) {
        #pragma unroll
        for (int fc = 0; fc < 4; ++fc) {
            const int n = (ocbase >> 4) + fc;
            #pragma unroll
            for (int j = 0; j < 4; ++j) {
                float v = acc[fr][fc][j];
                float s1 = v, s2 = v * v;
                #pragma unroll
                for (int off = 1; off < 16; off <<= 1) {
                    s1 += __shfl_xor(s1, off);
                    s2 += __shfl_xor(s2, off);
                }
                float mu  = s1 * (1.f / 16.f);
                float var = s2 * (1.f / 16.f) - mu * mu;
                float rs  = rsqrtf(var + EPSLN);
                float o   = (v - mu) * rs * gv + bv;
                int p  = pbase + wid * 32 + fr * 16 + hi * 4 + j;
                int oh = (p >> 4) & 15, ow = p & 15;
                val[(((b * 32 + n) * 16 + oh) * 16 + ow) * 16 + lo] = o;
            }
        }
    }
}

// ===================== fused caps routing (pass1 + pass2) + LN1 =====================
// Block = 2 sites (b=bb, b=bb+32) at (h,w). 8 half-wave groups (lane=m);
// group walks items it = n*9+kl step 8. u tile in LDS as bf16 (31.2 KB block
// LDS -> 5 blocks/CU). Softmax without max-subtract (5 cross-lane ops).
__global__ __launch_bounds__(256) void k_capsfused(const float* __restrict__ val,
                                                   const float* __restrict__ cw,
                                                   const float* __restrict__ g,
                                                   const float* __restrict__ bt,
                                                   float* __restrict__ vout) {
    int bb = blockIdx.x / 49;
    int hw = blockIdx.x % 49;
    int h = hw / 7, w = hw % 7;

    __shared__ uint4 ulocH[2][576];     // 18432 B  bf16 u tiles (item*2+half)
    __shared__ float wred[4 * 544];     //  8704 B  cross-wave reduce
    __shared__ float v1s[2][512];       //  4096 B  v1 / nv2 scratch

    for (int t = threadIdx.x; t < 1152; t += 256) {
        int s = t / 576, tt = t % 576;
        int item = tt >> 1, hf = tt & 1;
        int n = item / 9, kl = item % 9;
        int k = kl / 3, l = kl % 3;
        int b = bb + s * 32;
        const float4* src = (const float4*)(val +
            (((b * 32 + n) * 16 + (2 * h + k)) * 16 + (2 * w + l)) * 16 + hf * 8);
        ulocH[s][tt] = pack_bf16_8(src[0], src[1]);
    }

    const int lane  = threadIdx.x & 31;          // m
    const int grpid = threadIdx.x >> 5;          // 0..7
    const int wid   = threadIdx.x >> 6;          // 0..3
    const bool half0 = (threadIdx.x & 32) == 0;

    float nvacc[2][16];
    #pragma unroll
    for (int s = 0; s < 2; ++s)
        #pragma unroll
        for (int j = 0; j < 16; ++j) nvacc[s][j] = 0.f;

    __syncthreads();

    // ---------------- pass 1: nv1 = sum(votes)/32 ----------------
    for (int it = grpid; it < 288; it += 8) {
        int n  = it / 9;
        int kl = it % 9;
        const float* cwb = cw + (kl * 32 + n) * 512 + lane;
        float cwv[16];
        #pragma unroll
        for (int xd = 0; xd < 16; ++xd) cwv[xd] = cwb[xd * 32];
        #pragma unroll
        for (int s = 0; s < 2; ++s) {
            union { uint4 u; __bf16 hh[8]; } q0, q1;
            q0.u = ulocH[s][it * 2];
            q1.u = ulocH[s][it * 2 + 1];
            float u16[16];
            #pragma unroll
            for (int j = 0; j < 8; ++j) { u16[j] = (float)q0.hh[j]; u16[8 + j] = (float)q1.hh[j]; }
            #pragma unroll
            for (int a = 0; a < 4; ++a)
                #pragma unroll
                for (int d = 0; d < 4; ++d) {
                    #pragma unroll
                    for (int x = 0; x < 4; ++x)
                        nvacc[s][a * 4 + d] = fmaf(u16[a * 4 + x], cwv[x * 4 + d],
                                                   nvacc[s][a * 4 + d]);
                }
        }
    }

    // reduce: half-waves -> waves(LDS) -> nv1 -> LN -> v1s
    #pragma unroll
    for (int s = 0; s < 2; ++s)
        #pragma unroll
        for (int j = 0; j < 16; ++j)
            nvacc[s][j] += __shfl_xor(nvacc[s][j], 32);
    #pragma unroll
    for (int s = 0; s < 2; ++s) {
        __syncthreads();
        if (half0) {
            #pragma unroll
            for (int j = 0; j < 16; ++j) wred[wid * 544 + lane * 17 + j] = nvacc[s][j];
        }
        __syncthreads();
        for (int o = threadIdx.x; o < 512; o += 256) {
            int mm = o >> 4, j = o & 15;
            float sum = wred[0 * 544 + mm * 17 + j] + wred[1 * 544 + mm * 17 + j]
                      + wred[2 * 544 + mm * 17 + j] + wred[3 * 544 + mm * 17 + j];
            v1s[s][o] = sum * (1.f / 32.f);
        }
    }
    __syncthreads();
    if (threadIdx.x < 64) {       // LN per (s, m)
        int s = threadIdx.x >> 5, m = threadIdx.x & 31;
        float v16[16], mu = 0.f;
        #pragma unroll
        for (int j = 0; j < 16; ++j) { v16[j] = v1s[s][m * 16 + j]; mu += v16[j]; }
        mu *= (1.f / 16.f);
        float var = 0.f;
        #pragma unroll
        for (int j = 0; j < 16; ++j) { float t = v16[j] - mu; var += t * t; }
        var *= (1.f / 16.f);
        float rs = rsqrtf(var + EPSLN);
        #pragma unroll
        for (int j = 0; j < 16; ++j)
            v1s[s][m * 16 + j] = (v16[j] - mu) * rs * g[j] + bt[j];
    }
    __syncthreads();

    // ---------------- pass 2: routed ----------------
    float nvp[2][16];
    #pragma unroll
    for (int s = 0; s < 2; ++s)
        #pragma unroll
        for (int j = 0; j < 16; ++j) nvp[s][j] = v1s[s][lane * 16 + j];

    #pragma unroll
    for (int s = 0; s < 2; ++s)
        #pragma unroll
        for (int j = 0; j < 16; ++j) nvacc[s][j] = 0.f;

    for (int it = grpid; it < 288; it += 8) {
        int n  = it / 9;
        int kl = it % 9;
        const float* cwb = cw + (kl * 32 + n) * 512 + lane;
        float cwv[16];
        #pragma unroll
        for (int xd = 0; xd < 16; ++xd) cwv[xd] = cwb[xd * 32];
        #pragma unroll
        for (int s = 0; s < 2; ++s) {
            union { uint4 u; __bf16 hh[8]; } q0, q1;
            q0.u = ulocH[s][it * 2];
            q1.u = ulocH[s][it * 2 + 1];
            float u16[16];
            #pragma unroll
            for (int j = 0; j < 8; ++j) { u16[j] = (float)q0.hh[j]; u16[8 + j] = (float)q1.hh[j]; }
            float votes[16];
            #pragma unroll
            for (int a = 0; a < 4; ++a)
                #pragma unroll
                for (int d = 0; d < 4; ++d) {
                    float v = 0.f;
                    #pragma unroll
                    for (int x = 0; x < 4; ++x)
                        v = fmaf(u16[a * 4 + x], cwv[x * 4 + d], v);
                    votes[a * 4 + d] = v;
                }
            float qk = 0.f;
            #pragma unroll
            for (int j = 0; j < 16; ++j) qk = fmaf(votes[j], nvp[s][j], qk);
            qk *= 0.25f;                          // 1/sqrt(16)
            // softmax without max-subtract (shift-invariant); clamp for safety
            float e = __expf(fminf(fmaxf(qk, -30.f), 30.f));
            float sm = e;
            #pragma unroll
            for (int off = 1; off < 32; off <<= 1) sm += __shfl_xor(sm, off);
            float qv = e / sm;
            #pragma unroll
            for (int j = 0; j < 16; ++j) nvacc[s][j] = fmaf(qv, votes[j], nvacc[s][j]);
        }
    }

    // reduce pass 2 -> nv2 -> LN -> global
    #pragma unroll
    for (int s = 0; s < 2; ++s)
        #pragma unroll
        for (int j = 0; j < 16; ++j)
            nvacc[s][j] += __shfl_xor(nvacc[s][j], 32);
    #pragma unroll
    for (int s = 0; s < 2; ++s) {
        __syncthreads();
        if (half0) {
            #pragma unroll
            for (int j = 0; j < 16; ++j) wred[wid * 544 + lane * 17 + j] = nvacc[s][j];
        }
        __syncthreads();
        for (int o = threadIdx.x; o < 512; o += 256) {
            int mm = o >> 4, j = o & 15;
            float sum = wred[0 * 544 + mm * 17 + j] + wred[1 * 544 + mm * 17 + j]
                      + wred[2 * 544 + mm * 17 + j] + wred[3 * 544 + mm * 17 + j];
            v1s[s][o] = sum;
        }
    }
    __syncthreads();
    if (threadIdx.x < 64) {
        int s = threadIdx.x >> 5, m = threadIdx.x & 31;
        int b = bb + s * 32;
        float v16[16], mu = 0.f;
        #pragma unroll
        for (int j = 0; j < 16; ++j) { v16[j] = v1s[s][m * 16 + j]; mu += v16[j]; }
        mu *= (1.f / 16.f);
        float var = 0.f;
        #pragma unroll
        for (int j = 0; j < 16; ++j) { float t = v16[j] - mu; var += t * t; }
        var *= (1.f / 16.f);
        float rs = rsqrtf(var + EPSLN);
        float o16[16];
        #pragma unroll
        for (int j = 0; j < 16; ++j) o16[j] = (v16[j] - mu) * rs * g[j] + bt[j];
        float4* dst = (float4*)(vout + (((b * 32 + m) * 7 + h) * 7 + w) * 16);
        dst[0] = make_float4(o16[0],  o16[1],  o16[2],  o16[3]);
        dst[1] = make_float4(o16[4],  o16[5],  o16[6],  o16[7]);
        dst[2] = make_float4(o16[8],  o16[9],  o16[10], o16[11]);
        dst[3] = make_float4(o16[12], o16[13], o16[14], o16[15]);
    }
}

// ===================== fc step1 + LN2: v2 -> p =====================
__global__ __launch_bounds__(256) void k_fc1(const float* __restrict__ fin,
                                             const float* __restrict__ fwp,
                                             const float* __restrict__ g,
                                             const float* __restrict__ bt,
                                             float* __restrict__ p) {
    int b = blockIdx.x / 10, m = blockIdx.x % 10;
    const float* fb = fin + b * 1568 * 16;
    const float* wb = fwp + m * 1568 * 16;
    float acc[16];
    #pragma unroll
    for (int j = 0; j < 16; ++j) acc[j] = 0.f;

    for (int n = threadIdx.x; n < 1568; n += 256) {
        const float4* u4 = (const float4*)(fb + n * 16);
        const float4* w4 = (const float4*)(wb + n * 16);
        float u16[16], w16[16];
        #pragma unroll
        for (int f = 0; f < 4; ++f) {
            float4 a = u4[f], bq = w4[f];
            u16[f * 4 + 0] = a.x;  u16[f * 4 + 1] = a.y;
            u16[f * 4 + 2] = a.z;  u16[f * 4 + 3] = a.w;
            w16[f * 4 + 0] = bq.x; w16[f * 4 + 1] = bq.y;
            w16[f * 4 + 2] = bq.z; w16[f * 4 + 3] = bq.w;
        }
        #pragma unroll
        for (int a = 0; a < 4; ++a)
            #pragma unroll
            for (int d = 0; d < 4; ++d) {
                float s = acc[a * 4 + d];
                #pragma unroll
                for (int x = 0; x < 4; ++x)
                    s = fmaf(u16[a * 4 + x], w16[x * 4 + d], s);
                acc[a * 4 + d] = s;
            }
    }
    #pragma unroll
    for (int j = 0; j < 16; ++j)
        #pragma unroll
        for (int off = 1; off < 64; off <<= 1)
            acc[j] += __shfl_xor(acc[j], off);

    __shared__ float red[4][16];
    int wid = threadIdx.x >> 6, ln = threadIdx.x & 63;
    if (ln == 0) {
        #pragma unroll
        for (int j = 0; j < 16; ++j) red[wid][j] = acc[j];
    }
    __syncthreads();
    if (threadIdx.x < 16) {
        int j = threadIdx.x;
        float s = (red[0][j] + red[1][j] + red[2][j] + red[3][j]) * 0.1f;
        float mu = s;
        #pragma unroll
        for (int off = 1; off < 16; off <<= 1) mu += __shfl_xor(mu, off);
        mu *= (1.f / 16.f);
        float t = s - mu;
        float var = t * t;
        #pragma unroll
        for (int off = 1; off < 16; off <<= 1) var += __shfl_xor(var, off);
        var *= (1.f / 16.f);
        float rs = rsqrtf(var + EPSLN);
        p[(b * 10 + m) * 16 + j] = t * rs * g[j] + bt[j];
    }
}

// ===================== fc routing + LN2: v2,p -> out =====================
__global__ __launch_bounds__(256) void k_fc2(const float* __restrict__ fin,
                                             const float* __restrict__ fw,
                                             const float* __restrict__ p,
                                             const float* __restrict__ g,
                                             const float* __restrict__ bt,
                                             float* __restrict__ out) {
    int b = blockIdx.x;
    int ad    = threadIdx.x & 15;
    int grpid = threadIdx.x >> 4;
    int a = ad >> 2, d = ad & 3;

    float pv[10];
    #pragma unroll
    for (int m = 0; m < 10; ++m) pv[m] = p[(b * 10 + m) * 16 + ad];

    float acc[10];
    #pragma unroll
    for (int m = 0; m < 10; ++m) acc[m] = 0.f;

    const float* fb = fin + b * 1568 * 16;
    for (int n = grpid; n < 1568; n += 16) {
        float4 u4 = *(const float4*)(fb + n * 16 + a * 4);
        const float* wb = fw + n * 160 + d * 10;
        float votes[10];
        #pragma unroll
        for (int m = 0; m < 10; ++m)
            votes[m] = u4.x * wb[m] + u4.y * wb[40 + m] +
                       u4.z * wb[80 + m] + u4.w * wb[120 + m];
        float qk[10];
        #pragma unroll
        for (int m = 0; m < 10; ++m) {
            float t = votes[m] * pv[m];
            #pragma unroll
            for (int off = 1; off < 16; off <<= 1) t += __shfl_xor(t, off);
            qk[m] = t * 0.25f;
        }
        float mx = qk[0];
        #pragma unroll
        for (int m = 1; m < 10; ++m) mx = fmaxf(mx, qk[m]);
        float e[10], s = 0.f;
        #pragma unroll
        for (int m = 0; m < 10; ++m) { e[m] = __expf(qk[m] - mx); s += e[m]; }
        float inv = 1.f / s;
        #pragma unroll
        for (int m = 0; m < 10; ++m) acc[m] = fmaf(e[m] * inv, votes[m], acc[m]);
    }

    __shared__ float red[16][16][10];
    #pragma unroll
    for (int m = 0; m < 10; ++m) red[grpid][ad][m] = acc[m];
    __syncthreads();

    if (threadIdx.x < 160) {
        int m = threadIdx.x / 16, j = threadIdx.x % 16;
        float s = 0.f;
        #pragma unroll
        for (int gg = 0; gg < 16; ++gg) s += red[gg][j][m];
        float mu = s;
        #pragma unroll
        for (int off = 1; off < 16; off <<= 1) mu += __shfl_xor(mu, off);
        mu *= (1.f / 16.f);
        float t = s - mu;
        float var = t * t;
        #pragma unroll
        for (int off = 1; off < 16; off <<= 1) var += __shfl_xor(var, off);
        var *= (1.f / 16.f);
        float rs = rsqrtf(var + EPSLN);
        out[(b * 10 + m) * 16 + j] = t * rs * g[j] + bt[j];
    }
}

// ============================ launch ============================
extern "C" void kernel_launch(void* const* d_in, const int* in_sizes, int n_in,
                              void* d_out, int out_size, void* d_ws, size_t ws_size,
                              hipStream_t stream) {
    const float* x    = (const float*)d_in[0];
    const float* bbw  = (const float*)d_in[1];
    const float* bbb  = (const float*)d_in[2];
    const float* pcw  = (const float*)d_in[3];
    const float* ln0g = (const float*)d_in[4];
    const float* ln0b = (const float*)d_in[5];
    const float* cwt  = (const float*)d_in[6];
    const float* ln1g = (const float*)d_in[7];
    const float* ln1b = (const float*)d_in[8];
    const float* fw   = (const float*)d_in[9];
    const float* ln2g = (const float*)d_in[10];
    const float* ln2b = (const float*)d_in[11];
    float* outp = (float*)d_out;

    float* ws = (float*)d_ws;
    __bf16* c2p = (__bf16*)ws;                 // [0, 4,734,976)
    __bf16* wbT = (__bf16*)(ws + 4734976);     // [4,734,976, 5,029,888)
    float*  bwT = ws + 5029888;                // [5,029,888, 5,033,344)
    float*  val = ws + 5033344;                // [5,033,344, 13,421,952)
    float*  v2  = ws + 15027584;               // [15,027,584, 16,633,216)
    float*  fwp = ws + 16633216;               // [16,633,216, 16,884,096)
    float*  p   = ws + 16884096;               // [16,884,096, 16,894,336)

    hipMemsetAsync(c2p, 0, (size_t)9469952 * 2, stream);
    k_repack_bw  <<<14,   256, 0, stream>>>(bbw, bwT);
    k_repack_pcw <<<2304, 256, 0, stream>>>(pcw, wbT);
    k_repack_fw  <<<980,  256, 0, stream>>>(fw, fwp);
    k_conv1      <<<32768, 256, 0, stream>>>(x, bwT, bbb, c2p);
    k_conv2_mfma <<<1024, 256, 0, stream>>>(c2p, wbT, ln0g, ln0b, val);
    k_capsfused  <<<1568, 256, 0, stream>>>(val, cwt, ln1g, ln1b, v2);
    k_fc1        <<<640, 256, 0, stream>>>(v2, fwp, ln2g, ln2b, p);
    k_fc2        <<<64, 256, 0, stream>>>(v2, fw, p, ln2g, ln2b, outp);
}

// Round 9
// 466.090 us; speedup vs baseline: 1.2326x; 1.0006x over previous
//
#include <hip/hip_runtime.h>

// CapsTimeModel forward, round 9: capsfused latency diet.
//   - weights repacked to bf16 [kl][n][m][xd]: 2x dwordx4 per item per lane
//     (was 16 scalar stride-32 f32 loads); L2 bytes halved
//   - 2-deep software prefetch on the item loop (load it+8 while computing it)
// conv1/conv2/fc1/fc2 + rest of capsfused identical to R8 (passing, 466us).

#define EPSLN 1e-5f

typedef short  short8 __attribute__((ext_vector_type(8)));
typedef __bf16 bf16x8 __attribute__((ext_vector_type(8)));
typedef float  f32x4  __attribute__((ext_vector_type(4)));

union Frag { short8 s; bf16x8 b; };

__device__ __forceinline__ uint4 pack_bf16_8(float4 a, float4 b) {
    union { __bf16 h[8]; uint4 u; } r;
    r.h[0] = (__bf16)a.x; r.h[1] = (__bf16)a.y;
    r.h[2] = (__bf16)a.z; r.h[3] = (__bf16)a.w;
    r.h[4] = (__bf16)b.x; r.h[5] = (__bf16)b.y;
    r.h[6] = (__bf16)b.z; r.h[7] = (__bf16)b.w;
    return r.u;
}

// ============================ repack kernels ============================
__global__ __launch_bounds__(256) void k_repack_bw(const float* __restrict__ bw,
                                                   float* __restrict__ bwT) {
    int i = blockIdx.x * 256 + threadIdx.x;       // 128*27 = 3456
    if (i >= 3456) return;
    int oc = i / 27, r = i % 27;
    bwT[r * 128 + oc] = bw[i];
}

__global__ __launch_bounds__(256) void k_repack_pcw(const float* __restrict__ pw,
                                                    __bf16* __restrict__ wbT) {
    int i = blockIdx.x * 256 + threadIdx.x;       // 512*1152 = 589824 exact
    int oc = i / 1152, r = i % 1152;
    int ic = r / 9, tap = r % 9;
    wbT[oc * 1152 + tap * 128 + ic] = (__bf16)pw[i];
}

__global__ __launch_bounds__(256) void k_repack_fw(const float* __restrict__ fw,
                                                   float* __restrict__ fwp) {
    int i = blockIdx.x * 256 + threadIdx.x;       // 250880 exact
    int m = i % 10;
    int d = (i / 10) & 3;
    int x = (i / 40) & 3;
    int n = i / 160;
    fwp[(m * 1568 + n) * 16 + x * 4 + d] = fw[i];
}

// cw (kl,n,x,d,m) f32 -> cw2[kl][n][m][x*4+d] bf16  (147456 elements)
__global__ __launch_bounds__(256) void k_repack_cw2(const float* __restrict__ cw,
                                                    __bf16* __restrict__ cw2) {
    int i = blockIdx.x * 256 + threadIdx.x;       // 576 blocks -> 147456 exact
    int m  = i & 31;
    int d  = (i >> 5) & 3;
    int x  = (i >> 7) & 3;
    int n  = (i >> 9) & 31;
    int kl = i >> 14;
    cw2[(((kl * 32 + n) * 32) + m) * 16 + x * 4 + d] = (__bf16)cw[i];
}

// ==================== conv1: x -> c2p (NHWC bf16, padded) ====================
__global__ __launch_bounds__(256) void k_conv1(const float* __restrict__ x,
                                               const float* __restrict__ bwT,
                                               const float* __restrict__ bb,
                                               __bf16* __restrict__ c2p) {
    int gid = blockIdx.x * 256 + threadIdx.x;     // 64*32*32*128 = 8,388,608
    int oc = gid & 127;
    int p  = gid >> 7;
    int w = p & 31, h = (p >> 5) & 31, b = p >> 10;
    const float* xb = x + b * 3 * 64 * 64;
    float acc = bb[oc];
    #pragma unroll
    for (int ky = 0; ky < 3; ++ky) {
        int ih = 2 * h + ky - 1;
        if ((unsigned)ih >= 64u) continue;
        #pragma unroll
        for (int kx = 0; kx < 3; ++kx) {
            int iw = 2 * w + kx - 1;
            if ((unsigned)iw >= 64u) continue;
            #pragma unroll
            for (int ic = 0; ic < 3; ++ic)
                acc = fmaf(xb[(ic * 64 + ih) * 64 + iw],
                           bwT[(ic * 9 + ky * 3 + kx) * 128 + oc], acc);
        }
    }
    c2p[((b * 34 + h + 1) * 34 + (w + 1)) * 128 + oc] = (__bf16)fmaxf(acc, 0.f);
}

// ==================== conv2: MFMA GEMM + fused LN0 -> val ====================
__global__ __launch_bounds__(256) void k_conv2_mfma(const __bf16* __restrict__ c2p,
                                                    const __bf16* __restrict__ wbT,
                                                    const float* __restrict__ g,
                                                    const float* __restrict__ bt,
                                                    float* __restrict__ val) {
    __shared__ unsigned short sA[128 * 32];
    __shared__ unsigned short sB[64 * 32];

    const int t = threadIdx.x;
    const int mblk = blockIdx.x >> 3, nblk = blockIdx.x & 7;
    const int pbase = mblk * 128, ocbase = nblk * 64;
    const int b = pbase >> 8;

    const int r0 = t >> 2, r1 = r0 + 64;
    const int kc8 = (t & 3) * 8;
    const int oh0 = ((pbase + r0) >> 4) & 15, ow0 = (pbase + r0) & 15;
    const int oh1 = ((pbase + r1) >> 4) & 15, ow1 = (pbase + r1) & 15;

    const unsigned short* cb = (const unsigned short*)c2p + (size_t)b * 147968;
    const unsigned short* ws = (const unsigned short*)wbT
                               + (ocbase + (t >> 2)) * 1152 + kc8;

    const int lane = t & 63, wid = t >> 6;
    const int lo = lane & 15, hi = lane >> 4;

    f32x4 acc[2][4];
    #pragma unroll
    for (int fr = 0; fr < 2; ++fr)
        #pragma unroll
        for (int fc = 0; fc < 4; ++fc)
            acc[fr][fc] = (f32x4){0.f, 0.f, 0.f, 0.f};

    for (int ks = 0; ks < 36; ++ks) {
        const int tap = ks / 4;
        const int ic0 = (ks % 4) * 32;
        const int ty = tap / 3, tx = tap % 3;
        uint4 a0 = *(const uint4*)(cb + ((2 * oh0 + ty) * 34 + (2 * ow0 + tx)) * 128
                                      + ic0 + kc8);
        uint4 a1 = *(const uint4*)(cb + ((2 * oh1 + ty) * 34 + (2 * ow1 + tx)) * 128
                                      + ic0 + kc8);
        uint4 b0 = *(const uint4*)(ws + ks * 32);
        __syncthreads();
        *(uint4*)&sA[(unsigned)t * 8]         = a0;
        *(uint4*)&sA[((unsigned)t + 256) * 8] = a1;
        *(uint4*)&sB[(unsigned)t * 8]         = b0;
        __syncthreads();

        Frag af0, af1, bf[4];
        af0.s = *(const short8*)&sA[(wid * 32 + lo) * 32 + hi * 8];
        af1.s = *(const short8*)&sA[(wid * 32 + 16 + lo) * 32 + hi * 8];
        #pragma unroll
        for (int fc = 0; fc < 4; ++fc)
            bf[fc].s = *(const short8*)&sB[(fc * 16 + lo) * 32 + hi * 8];
        #pragma unroll
        for (int fc = 0; fc < 4; ++fc) {
            acc[0][fc] = __builtin_amdgcn_mfma_f32_16x16x32_bf16(
                af0.b, bf[fc].b, acc[0][fc], 0, 0, 0);
            acc[1][fc] = __builtin_amdgcn_mfma_f32_16x16x32_bf16(
                af1.b, bf[fc].b, acc[1][fc], 0, 0, 0);
        }
    }

    const float gv = g[lo], bv = bt[lo];
    #pragma unroll
    for (int fr = 0; fr < 2; ++fr) {
        #pragma unroll
        for (int fc = 0; fc < 4; ++fc) {
            const int n = (ocbase >> 4) + fc;
            #pragma unroll
            for (int j = 0; j < 4; ++j) {
                float v = acc[fr][fc][j];
                float s1 = v, s2 = v * v;
                #pragma unroll
                for (int off = 1; off < 16; off <<= 1) {
                    s1 += __shfl_xor(s1, off);
                    s2 += __shfl_xor(s2, off);
                }
                float mu  = s1 * (1.f / 16.f);
                float var = s2 * (1.f / 16.f) - mu * mu;
                float rs  = rsqrtf(var + EPSLN);
                float o   = (v - mu) * rs * gv + bv;
                int p  = pbase + wid * 32 + fr * 16 + hi * 4 + j;
                int oh = (p >> 4) & 15, ow = p & 15;
                val[(((b * 32 + n) * 16 + oh) * 16 + ow) * 16 + lo] = o;
            }
        }
    }
}

// ===================== fused caps routing (pass1 + pass2) + LN1 =====================
// Block = 2 sites (b=bb, b=bb+32) at (h,w). 8 half-wave groups (lane=m);
// group walks items it = n*9+kl step 8 (36 each). u tile in LDS as bf16.
// Weights: bf16 [kl][n][m][xd] -> 2x dwordx4 per item, 2-deep prefetched.
__global__ __launch_bounds__(256) void k_capsfused(const float* __restrict__ val,
                                                   const __bf16* __restrict__ cw2,
                                                   const float* __restrict__ g,
                                                   const float* __restrict__ bt,
                                                   float* __restrict__ vout) {
    int bb = blockIdx.x / 49;
    int hw = blockIdx.x % 49;
    int h = hw / 7, w = hw % 7;

    __shared__ uint4 ulocH[2][576];     // 18432 B  bf16 u tiles (item*2+half)
    __shared__ float wred[4 * 544];     //  8704 B  cross-wave reduce
    __shared__ float v1s[2][512];       //  4096 B  v1 / nv2 scratch

    for (int t = threadIdx.x; t < 1152; t += 256) {
        int s = t / 576, tt = t % 576;
        int item = tt >> 1, hf = tt & 1;
        int n = item / 9, kl = item % 9;
        int k = kl / 3, l = kl % 3;
        int b = bb + s * 32;
        const float4* src = (const float4*)(val +
            (((b * 32 + n) * 16 + (2 * h + k)) * 16 + (2 * w + l)) * 16 + hf * 8);
        ulocH[s][tt] = pack_bf16_8(src[0], src[1]);
    }

    const int lane  = threadIdx.x & 31;          // m
    const int grpid = threadIdx.x >> 5;          // 0..7
    const int wid   = threadIdx.x >> 6;          // 0..3
    const bool half0 = (threadIdx.x & 32) == 0;

    float nvacc[2][16];
    #pragma unroll
    for (int s = 0; s < 2; ++s)
        #pragma unroll
        for (int j = 0; j < 16; ++j) nvacc[s][j] = 0.f;

    __syncthreads();

    // ---------------- pass 1: nv1 = sum(votes)/32 ----------------
    {
        uint4 wq0, wq1;
        {
            int n = grpid / 9, kl = grpid % 9;
            const uint4* wb = (const uint4*)(cw2 + (((kl * 32 + n) * 32) + lane) * 16);
            wq0 = wb[0]; wq1 = wb[1];
        }
        for (int it = grpid; it < 288; it += 8) {
            int nit = it + 8;
            uint4 nq0 = wq0, nq1 = wq1;
            if (nit < 288) {
                int n = nit / 9, kl = nit % 9;
                const uint4* wb = (const uint4*)(cw2 + (((kl * 32 + n) * 32) + lane) * 16);
                nq0 = wb[0]; nq1 = wb[1];
            }
            float cwv[16];
            {
                union { uint4 u; __bf16 hh[8]; } qa, qb;
                qa.u = wq0; qb.u = wq1;
                #pragma unroll
                for (int j = 0; j < 8; ++j) {
                    cwv[j] = (float)qa.hh[j]; cwv[8 + j] = (float)qb.hh[j];
                }
            }
            #pragma unroll
            for (int s = 0; s < 2; ++s) {
                union { uint4 u; __bf16 hh[8]; } q0, q1;
                q0.u = ulocH[s][it * 2];
                q1.u = ulocH[s][it * 2 + 1];
                float u16[16];
                #pragma unroll
                for (int j = 0; j < 8; ++j) { u16[j] = (float)q0.hh[j]; u16[8 + j] = (float)q1.hh[j]; }
                #pragma unroll
                for (int a = 0; a < 4; ++a)
                    #pragma unroll
                    for (int d = 0; d < 4; ++d) {
                        #pragma unroll
                        for (int x = 0; x < 4; ++x)
                            nvacc[s][a * 4 + d] = fmaf(u16[a * 4 + x], cwv[x * 4 + d],
                                                       nvacc[s][a * 4 + d]);
                    }
            }
            wq0 = nq0; wq1 = nq1;
        }
    }

    // reduce: half-waves -> waves(LDS) -> nv1 -> LN -> v1s
    #pragma unroll
    for (int s = 0; s < 2; ++s)
        #pragma unroll
        for (int j = 0; j < 16; ++j)
            nvacc[s][j] += __shfl_xor(nvacc[s][j], 32);
    #pragma unroll
    for (int s = 0; s < 2; ++s) {
        __syncthreads();
        if (half0) {
            #pragma unroll
            for (int j = 0; j < 16; ++j) wred[wid * 544 + lane * 17 + j] = nvacc[s][j];
        }
        __syncthreads();
        for (int o = threadIdx.x; o < 512; o += 256) {
            int mm = o >> 4, j = o & 15;
            float sum = wred[0 * 544 + mm * 17 + j] + wred[1 * 544 + mm * 17 + j]
                      + wred[2 * 544 + mm * 17 + j] + wred[3 * 544 + mm * 17 + j];
            v1s[s][o] = sum * (1.f / 32.f);
        }
    }
    __syncthreads();
    if (threadIdx.x < 64) {       // LN per (s, m)
        int s = threadIdx.x >> 5, m = threadIdx.x & 31;
        float v16[16], mu = 0.f;
        #pragma unroll
        for (int j = 0; j < 16; ++j) { v16[j] = v1s[s][m * 16 + j]; mu += v16[j]; }
        mu *= (1.f / 16.f);
        float var = 0.f;
        #pragma unroll
        for (int j = 0; j < 16; ++j) { float t = v16[j] - mu; var += t * t; }
        var *= (1.f / 16.f);
        float rs = rsqrtf(var + EPSLN);
        #pragma unroll
        for (int j = 0; j < 16; ++j)
            v1s[s][m * 16 + j] = (v16[j] - mu) * rs * g[j] + bt[j];
    }
    __syncthreads();

    // ---------------- pass 2: routed ----------------
    float nvp[2][16];
    #pragma unroll
    for (int s = 0; s < 2; ++s)
        #pragma unroll
        for (int j = 0; j < 16; ++j) nvp[s][j] = v1s[s][lane * 16 + j];

    #pragma unroll
    for (int s = 0; s < 2; ++s)
        #pragma unroll
        for (int j = 0; j < 16; ++j) nvacc[s][j] = 0.f;

    {
        uint4 wq0, wq1;
        {
            int n = grpid / 9, kl = grpid % 9;
            const uint4* wb = (const uint4*)(cw2 + (((kl * 32 + n) * 32) + lane) * 16);
            wq0 = wb[0]; wq1 = wb[1];
        }
        for (int it = grpid; it < 288; it += 8) {
            int nit = it + 8;
            uint4 nq0 = wq0, nq1 = wq1;
            if (nit < 288) {
                int n = nit / 9, kl = nit % 9;
                const uint4* wb = (const uint4*)(cw2 + (((kl * 32 + n) * 32) + lane) * 16);
                nq0 = wb[0]; nq1 = wb[1];
            }
            float cwv[16];
            {
                union { uint4 u; __bf16 hh[8]; } qa, qb;
                qa.u = wq0; qb.u = wq1;
                #pragma unroll
                for (int j = 0; j < 8; ++j) {
                    cwv[j] = (float)qa.hh[j]; cwv[8 + j] = (float)qb.hh[j];
                }
            }
            #pragma unroll
            for (int s = 0; s < 2; ++s) {
                union { uint4 u; __bf16 hh[8]; } q0, q1;
                q0.u = ulocH[s][it * 2];
                q1.u = ulocH[s][it * 2 + 1];
                float u16[16];
                #pragma unroll
                for (int j = 0; j < 8; ++j) { u16[j] = (float)q0.hh[j]; u16[8 + j] = (float)q1.hh[j]; }
                float votes[16];
                #pragma unroll
                for (int a = 0; a < 4; ++a)
                    #pragma unroll
                    for (int d = 0; d < 4; ++d) {
                        float v = 0.f;
                        #pragma unroll
                        for (int x = 0; x < 4; ++x)
                            v = fmaf(u16[a * 4 + x], cwv[x * 4 + d], v);
                        votes[a * 4 + d] = v;
                    }
                float qk = 0.f;
                #pragma unroll
                for (int j = 0; j < 16; ++j) qk = fmaf(votes[j], nvp[s][j], qk);
                qk *= 0.25f;                          // 1/sqrt(16)
                float e = __expf(fminf(fmaxf(qk, -30.f), 30.f));
                float sm = e;
                #pragma unroll
                for (int off = 1; off < 32; off <<= 1) sm += __shfl_xor(sm, off);
                float qv = e / sm;
                #pragma unroll
                for (int j = 0; j < 16; ++j) nvacc[s][j] = fmaf(qv, votes[j], nvacc[s][j]);
            }
            wq0 = nq0; wq1 = nq1;
        }
    }

    // reduce pass 2 -> nv2 -> LN -> global
    #pragma unroll
    for (int s = 0; s < 2; ++s)
        #pragma unroll
        for (int j = 0; j < 16; ++j)
            nvacc[s][j] += __shfl_xor(nvacc[s][j], 32);
    #pragma unroll
    for (int s = 0; s < 2; ++s) {
        __syncthreads();
        if (half0) {
            #pragma unroll
            for (int j = 0; j < 16; ++j) wred[wid * 544 + lane * 17 + j] = nvacc[s][j];
        }
        __syncthreads();
        for (int o = threadIdx.x; o < 512; o += 256) {
            int mm = o >> 4, j = o & 15;
            float sum = wred[0 * 544 + mm * 17 + j] + wred[1 * 544 + mm * 17 + j]
                      + wred[2 * 544 + mm * 17 + j] + wred[3 * 544 + mm * 17 + j];
            v1s[s][o] = sum;
        }
    }
    __syncthreads();
    if (threadIdx.x < 64) {
        int s = threadIdx.x >> 5, m = threadIdx.x & 31;
        int b = bb + s * 32;
        float v16[16], mu = 0.f;
        #pragma unroll
        for (int j = 0; j < 16; ++j) { v16[j] = v1s[s][m * 16 + j]; mu += v16[j]; }
        mu *= (1.f / 16.f);
        float var = 0.f;
        #pragma unroll
        for (int j = 0; j < 16; ++j) { float t = v16[j] - mu; var += t * t; }
        var *= (1.f / 16.f);
        float rs = rsqrtf(var + EPSLN);
        float o16[16];
        #pragma unroll
        for (int j = 0; j < 16; ++j) o16[j] = (v16[j] - mu) * rs * g[j] + bt[j];
        float4* dst = (float4*)(vout + (((b * 32 + m) * 7 + h) * 7 + w) * 16);
        dst[0] = make_float4(o16[0],  o16[1],  o16[2],  o16[3]);
        dst[1] = make_float4(o16[4],  o16[5],  o16[6],  o16[7]);
        dst[2] = make_float4(o16[8],  o16[9],  o16[10], o16[11]);
        dst[3] = make_float4(o16[12], o16[13], o16[14], o16[15]);
    }
}

// ===================== fc step1 + LN2: v2 -> p =====================
__global__ __launch_bounds__(256) void k_fc1(const float* __restrict__ fin,
                                             const float* __restrict__ fwp,
                                             const float* __restrict__ g,
                                             const float* __restrict__ bt,
                                             float* __restrict__ p) {
    int b = blockIdx.x / 10, m = blockIdx.x % 10;
    const float* fb = fin + b * 1568 * 16;
    const float* wb = fwp + m * 1568 * 16;
    float acc[16];
    #pragma unroll
    for (int j = 0; j < 16; ++j) acc[j] = 0.f;

    for (int n = threadIdx.x; n < 1568; n += 256) {
        const float4* u4 = (const float4*)(fb + n * 16);
        const float4* w4 = (const float4*)(wb + n * 16);
        float u16[16], w16[16];
        #pragma unroll
        for (int f = 0; f < 4; ++f) {
            float4 a = u4[f], bq = w4[f];
            u16[f * 4 + 0] = a.x;  u16[f * 4 + 1] = a.y;
            u16[f * 4 + 2] = a.z;  u16[f * 4 + 3] = a.w;
            w16[f * 4 + 0] = bq.x; w16[f * 4 + 1] = bq.y;
            w16[f * 4 + 2] = bq.z; w16[f * 4 + 3] = bq.w;
        }
        #pragma unroll
        for (int a = 0; a < 4; ++a)
            #pragma unroll
            for (int d = 0; d < 4; ++d) {
                float s = acc[a * 4 + d];
                #pragma unroll
                for (int x = 0; x < 4; ++x)
                    s = fmaf(u16[a * 4 + x], w16[x * 4 + d], s);
                acc[a * 4 + d] = s;
            }
    }
    #pragma unroll
    for (int j = 0; j < 16; ++j)
        #pragma unroll
        for (int off = 1; off < 64; off <<= 1)
            acc[j] += __shfl_xor(acc[j], off);

    __shared__ float red[4][16];
    int wid = threadIdx.x >> 6, ln = threadIdx.x & 63;
    if (ln == 0) {
        #pragma unroll
        for (int j = 0; j < 16; ++j) red[wid][j] = acc[j];
    }
    __syncthreads();
    if (threadIdx.x < 16) {
        int j = threadIdx.x;
        float s = (red[0][j] + red[1][j] + red[2][j] + red[3][j]) * 0.1f;
        float mu = s;
        #pragma unroll
        for (int off = 1; off < 16; off <<= 1) mu += __shfl_xor(mu, off);
        mu *= (1.f / 16.f);
        float t = s - mu;
        float var = t * t;
        #pragma unroll
        for (int off = 1; off < 16; off <<= 1) var += __shfl_xor(var, off);
        var *= (1.f / 16.f);
        float rs = rsqrtf(var + EPSLN);
        p[(b * 10 + m) * 16 + j] = t * rs * g[j] + bt[j];
    }
}

// ===================== fc routing + LN2: v2,p -> out =====================
__global__ __launch_bounds__(256) void k_fc2(const float* __restrict__ fin,
                                             const float* __restrict__ fw,
                                             const float* __restrict__ p,
                                             const float* __restrict__ g,
                                             const float* __restrict__ bt,
                                             float* __restrict__ out) {
    int b = blockIdx.x;
    int ad    = threadIdx.x & 15;
    int grpid = threadIdx.x >> 4;
    int a = ad >> 2, d = ad & 3;

    float pv[10];
    #pragma unroll
    for (int m = 0; m < 10; ++m) pv[m] = p[(b * 10 + m) * 16 + ad];

    float acc[10];
    #pragma unroll
    for (int m = 0; m < 10; ++m) acc[m] = 0.f;

    const float* fb = fin + b * 1568 * 16;
    for (int n = grpid; n < 1568; n += 16) {
        float4 u4 = *(const float4*)(fb + n * 16 + a * 4);
        const float* wb = fw + n * 160 + d * 10;
        float votes[10];
        #pragma unroll
        for (int m = 0; m < 10; ++m)
            votes[m] = u4.x * wb[m] + u4.y * wb[40 + m] +
                       u4.z * wb[80 + m] + u4.w * wb[120 + m];
        float qk[10];
        #pragma unroll
        for (int m = 0; m < 10; ++m) {
            float t = votes[m] * pv[m];
            #pragma unroll
            for (int off = 1; off < 16; off <<= 1) t += __shfl_xor(t, off);
            qk[m] = t * 0.25f;
        }
        float mx = qk[0];
        #pragma unroll
        for (int m = 1; m < 10; ++m) mx = fmaxf(mx, qk[m]);
        float e[10], s = 0.f;
        #pragma unroll
        for (int m = 0; m < 10; ++m) { e[m] = __expf(qk[m] - mx); s += e[m]; }
        float inv = 1.f / s;
        #pragma unroll
        for (int m = 0; m < 10; ++m) acc[m] = fmaf(e[m] * inv, votes[m], acc[m]);
    }

    __shared__ float red[16][16][10];
    #pragma unroll
    for (int m = 0; m < 10; ++m) red[grpid][ad][m] = acc[m];
    __syncthreads();

    if (threadIdx.x < 160) {
        int m = threadIdx.x / 16, j = threadIdx.x % 16;
        float s = 0.f;
        #pragma unroll
        for (int gg = 0; gg < 16; ++gg) s += red[gg][j][m];
        float mu = s;
        #pragma unroll
        for (int off = 1; off < 16; off <<= 1) mu += __shfl_xor(mu, off);
        mu *= (1.f / 16.f);
        float t = s - mu;
        float var = t * t;
        #pragma unroll
        for (int off = 1; off < 16; off <<= 1) var += __shfl_xor(var, off);
        var *= (1.f / 16.f);
        float rs = rsqrtf(var + EPSLN);
        out[(b * 10 + m) * 16 + j] = t * rs * g[j] + bt[j];
    }
}

// ============================ launch ============================
extern "C" void kernel_launch(void* const* d_in, const int* in_sizes, int n_in,
                              void* d_out, int out_size, void* d_ws, size_t ws_size,
                              hipStream_t stream) {
    const float* x    = (const float*)d_in[0];
    const float* bbw  = (const float*)d_in[1];
    const float* bbb  = (const float*)d_in[2];
    const float* pcw  = (const float*)d_in[3];
    const float* ln0g = (const float*)d_in[4];
    const float* ln0b = (const float*)d_in[5];
    const float* cwt  = (const float*)d_in[6];
    const float* ln1g = (const float*)d_in[7];
    const float* ln1b = (const float*)d_in[8];
    const float* fw   = (const float*)d_in[9];
    const float* ln2g = (const float*)d_in[10];
    const float* ln2b = (const float*)d_in[11];
    float* outp = (float*)d_out;

    float* ws = (float*)d_ws;
    __bf16* c2p = (__bf16*)ws;                 // [0, 4,734,976)
    __bf16* wbT = (__bf16*)(ws + 4734976);     // [4,734,976, 5,029,888)
    float*  bwT = ws + 5029888;                // [5,029,888, 5,033,344)
    float*  val = ws + 5033344;                // [5,033,344, 13,421,952)
    float*  v2  = ws + 15027584;               // [15,027,584, 16,633,216)
    float*  fwp = ws + 16633216;               // [16,633,216, 16,884,096)
    float*  p   = ws + 16884096;               // [16,884,096, 16,894,336)
    __bf16* cw2 = (__bf16*)(ws + 16894336);    // [16,894,336, 16,968,064) ~67.9MB

    hipMemsetAsync(c2p, 0, (size_t)9469952 * 2, stream);
    k_repack_bw  <<<14,   256, 0, stream>>>(bbw, bwT);
    k_repack_pcw <<<2304, 256, 0, stream>>>(pcw, wbT);
    k_repack_fw  <<<980,  256, 0, stream>>>(fw, fwp);
    k_repack_cw2 <<<576,  256, 0, stream>>>(cwt, cw2);
    k_conv1      <<<32768, 256, 0, stream>>>(x, bwT, bbb, c2p);
    k_conv2_mfma <<<1024, 256, 0, stream>>>(c2p, wbT, ln0g, ln0b, val);
    k_capsfused  <<<1568, 256, 0, stream>>>(val, cw2, ln1g, ln1b, v2);
    k_fc1        <<<640, 256, 0, stream>>>(v2, fwp, ln2g, ln2b, p);
    k_fc2        <<<64, 256, 0, stream>>>(v2, fw, p, ln2g, ln2b, outp);
}

// Round 11
// 448.933 us; speedup vs baseline: 1.2797x; 1.0382x over previous
//
#include <hip/hip_runtime.h>

// CapsTimeModel forward, round 11: R10 with FIXED workspace layout.
// R10 bug: cw2 = 147456 bf16 = 73728 f32 but was given 36864 f32; cwB was
// placed inside cw2 -> repack clobbered half the pass-2 weights. All extents
// re-derived and compacted this round; kernels identical to R10.

#define EPSLN 1e-5f

typedef short  short8 __attribute__((ext_vector_type(8)));
typedef __bf16 bf16x8 __attribute__((ext_vector_type(8)));
typedef float  f32x4  __attribute__((ext_vector_type(4)));

union Frag { short8 s; bf16x8 b; };

__device__ __forceinline__ uint4 pack_bf16_8(float4 a, float4 b) {
    union { __bf16 h[8]; uint4 u; } r;
    r.h[0] = (__bf16)a.x; r.h[1] = (__bf16)a.y;
    r.h[2] = (__bf16)a.z; r.h[3] = (__bf16)a.w;
    r.h[4] = (__bf16)b.x; r.h[5] = (__bf16)b.y;
    r.h[6] = (__bf16)b.z; r.h[7] = (__bf16)b.w;
    return r.u;
}

// ============================ repack kernels ============================
__global__ __launch_bounds__(256) void k_repack_bw(const float* __restrict__ bw,
                                                   float* __restrict__ bwT) {
    int i = blockIdx.x * 256 + threadIdx.x;       // 128*27 = 3456
    if (i >= 3456) return;
    int oc = i / 27, r = i % 27;
    bwT[r * 128 + oc] = bw[i];
}

__global__ __launch_bounds__(256) void k_repack_pcw(const float* __restrict__ pw,
                                                    __bf16* __restrict__ wbT) {
    int i = blockIdx.x * 256 + threadIdx.x;       // 512*1152 = 589824 exact
    int oc = i / 1152, r = i % 1152;
    int ic = r / 9, tap = r % 9;
    wbT[oc * 1152 + tap * 128 + ic] = (__bf16)pw[i];
}

__global__ __launch_bounds__(256) void k_repack_fw(const float* __restrict__ fw,
                                                   float* __restrict__ fwp) {
    int i = blockIdx.x * 256 + threadIdx.x;       // 250880 exact
    int m = i % 10;
    int d = (i / 10) & 3;
    int x = (i / 40) & 3;
    int n = i / 160;
    fwp[(m * 1568 + n) * 16 + x * 4 + d] = fw[i];
}

// cw (kl,n,x,d,m) f32 -> cw2[kl][n][m][x*4+d] bf16  (pass-2 weights)
__global__ __launch_bounds__(256) void k_repack_cw2(const float* __restrict__ cw,
                                                    __bf16* __restrict__ cw2) {
    int i = blockIdx.x * 256 + threadIdx.x;       // 576 blocks -> 147456 exact
    int m  = i & 31;
    int d  = (i >> 5) & 3;
    int x  = (i >> 7) & 3;
    int n  = (i >> 9) & 31;
    int kl = i >> 14;
    cw2[(((kl * 32 + n) * 32) + m) * 16 + x * 4 + d] = (__bf16)cw[i];
}

// cw (kl,n,x,d,m) f32 -> cwB[m*4+d][(n*9+kl)*4+x] bf16  (nv1-GEMM B^T)
__global__ __launch_bounds__(256) void k_repack_cwB(const float* __restrict__ cw,
                                                    __bf16* __restrict__ cwB) {
    int i = blockIdx.x * 256 + threadIdx.x;       // 147456 exact
    int m  = i & 31;
    int d  = (i >> 5) & 3;
    int x  = (i >> 7) & 3;
    int n  = (i >> 9) & 31;
    int kl = i >> 14;
    cwB[(m * 4 + d) * 1152 + (n * 9 + kl) * 4 + x] = (__bf16)cw[i];
}

// ==================== conv1: x -> c2p (NHWC bf16, padded) ====================
__global__ __launch_bounds__(256) void k_conv1(const float* __restrict__ x,
                                               const float* __restrict__ bwT,
                                               const float* __restrict__ bb,
                                               __bf16* __restrict__ c2p) {
    int gid = blockIdx.x * 256 + threadIdx.x;     // 64*32*32*128 = 8,388,608
    int oc = gid & 127;
    int p  = gid >> 7;
    int w = p & 31, h = (p >> 5) & 31, b = p >> 10;
    const float* xb = x + b * 3 * 64 * 64;
    float acc = bb[oc];
    #pragma unroll
    for (int ky = 0; ky < 3; ++ky) {
        int ih = 2 * h + ky - 1;
        if ((unsigned)ih >= 64u) continue;
        #pragma unroll
        for (int kx = 0; kx < 3; ++kx) {
            int iw = 2 * w + kx - 1;
            if ((unsigned)iw >= 64u) continue;
            #pragma unroll
            for (int ic = 0; ic < 3; ++ic)
                acc = fmaf(xb[(ic * 64 + ih) * 64 + iw],
                           bwT[(ic * 9 + ky * 3 + kx) * 128 + oc], acc);
        }
    }
    c2p[((b * 34 + h + 1) * 34 + (w + 1)) * 128 + oc] = (__bf16)fmaxf(acc, 0.f);
}

// ==================== conv2: MFMA GEMM + fused LN0 -> val ====================
__global__ __launch_bounds__(256) void k_conv2_mfma(const __bf16* __restrict__ c2p,
                                                    const __bf16* __restrict__ wbT,
                                                    const float* __restrict__ g,
                                                    const float* __restrict__ bt,
                                                    float* __restrict__ val) {
    __shared__ unsigned short sA[128 * 32];
    __shared__ unsigned short sB[64 * 32];

    const int t = threadIdx.x;
    const int mblk = blockIdx.x >> 3, nblk = blockIdx.x & 7;
    const int pbase = mblk * 128, ocbase = nblk * 64;
    const int b = pbase >> 8;

    const int r0 = t >> 2, r1 = r0 + 64;
    const int kc8 = (t & 3) * 8;
    const int oh0 = ((pbase + r0) >> 4) & 15, ow0 = (pbase + r0) & 15;
    const int oh1 = ((pbase + r1) >> 4) & 15, ow1 = (pbase + r1) & 15;

    const unsigned short* cb = (const unsigned short*)c2p + (size_t)b * 147968;
    const unsigned short* ws = (const unsigned short*)wbT
                               + (ocbase + (t >> 2)) * 1152 + kc8;

    const int lane = t & 63, wid = t >> 6;
    const int lo = lane & 15, hi = lane >> 4;

    f32x4 acc[2][4];
    #pragma unroll
    for (int fr = 0; fr < 2; ++fr)
        #pragma unroll
        for (int fc = 0; fc < 4; ++fc)
            acc[fr][fc] = (f32x4){0.f, 0.f, 0.f, 0.f};

    for (int ks = 0; ks < 36; ++ks) {
        const int tap = ks / 4;
        const int ic0 = (ks % 4) * 32;
        const int ty = tap / 3, tx = tap % 3;
        uint4 a0 = *(const uint4*)(cb + ((2 * oh0 + ty) * 34 + (2 * ow0 + tx)) * 128
                                      + ic0 + kc8);
        uint4 a1 = *(const uint4*)(cb + ((2 * oh1 + ty) * 34 + (2 * ow1 + tx)) * 128
                                      + ic0 + kc8);
        uint4 b0 = *(const uint4*)(ws + ks * 32);
        __syncthreads();
        *(uint4*)&sA[(unsigned)t * 8]         = a0;
        *(uint4*)&sA[((unsigned)t + 256) * 8] = a1;
        *(uint4*)&sB[(unsigned)t * 8]         = b0;
        __syncthreads();

        Frag af0, af1, bf[4];
        af0.s = *(const short8*)&sA[(wid * 32 + lo) * 32 + hi * 8];
        af1.s = *(const short8*)&sA[(wid * 32 + 16 + lo) * 32 + hi * 8];
        #pragma unroll
        for (int fc = 0; fc < 4; ++fc)
            bf[fc].s = *(const short8*)&sB[(fc * 16 + lo) * 32 + hi * 8];
        #pragma unroll
        for (int fc = 0; fc < 4; ++fc) {
            acc[0][fc] = __builtin_amdgcn_mfma_f32_16x16x32_bf16(
                af0.b, bf[fc].b, acc[0][fc], 0, 0, 0);
            acc[1][fc] = __builtin_amdgcn_mfma_f32_16x16x32_bf16(
                af1.b, bf[fc].b, acc[1][fc], 0, 0, 0);
        }
    }

    const float gv = g[lo], bv = bt[lo];
    #pragma unroll
    for (int fr = 0; fr < 2; ++fr) {
        #pragma unroll
        for (int fc = 0; fc < 4; ++fc) {
            const int n = (ocbase >> 4) + fc;
            #pragma unroll
            for (int j = 0; j < 4; ++j) {
                float v = acc[fr][fc][j];
                float s1 = v, s2 = v * v;
                #pragma unroll
                for (int off = 1; off < 16; off <<= 1) {
                    s1 += __shfl_xor(s1, off);
                    s2 += __shfl_xor(s2, off);
                }
                float mu  = s1 * (1.f / 16.f);
                float var = s2 * (1.f / 16.f) - mu * mu;
                float rs  = rsqrtf(var + EPSLN);
                float o   = (v - mu) * rs * gv + bv;
                int p  = pbase + wid * 32 + fr * 16 + hi * 4 + j;
                int oh = (p >> 4) & 15, ow = p & 15;
                val[(((b * 32 + n) * 16 + oh) * 16 + ow) * 16 + lo] = o;
            }
        }
    }
}

// ==================== nv1 GEMM: val x cwB -> nv1g (raw f32) ====================
// M = 12544 (row = site*4+a, site = b*49+hw), K = 1152 (k=(n*9+kl)*4+x),
// N = 128 (col = m*4+d). A staged from val on the fly (f32 -> bf16 pack).
__global__ __launch_bounds__(256) void k_nv1_mfma(const float* __restrict__ val,
                                                  const __bf16* __restrict__ cwB,
                                                  float* __restrict__ nv1g) {
    __shared__ unsigned short sA[128 * 32];
    __shared__ unsigned short sB[64 * 32];

    const int t = threadIdx.x;
    const int mblk = blockIdx.x >> 1, nblk = blockIdx.x & 1;
    const int pbase = mblk * 128, ocbase = nblk * 64;

    const float* vbase[2];
    #pragma unroll
    for (int u = 0; u < 2; ++u) {
        int r = pbase + (t >> 2) + u * 64;
        int site = r >> 2, a = r & 3;
        int b = site / 49, hw = site % 49;
        int h = hw / 7, w = hw % 7;
        vbase[u] = val + (size_t)b * 131072 + (2 * h) * 256 + (2 * w) * 16 + a * 4;
    }
    const unsigned short* wsrc = (const unsigned short*)cwB
                                 + (ocbase + (t >> 2)) * 1152 + (t & 3) * 8;

    const int lane = t & 63, wid = t >> 6;
    const int lo = lane & 15, hi = lane >> 4;

    f32x4 acc[2][4];
    #pragma unroll
    for (int fr = 0; fr < 2; ++fr)
        #pragma unroll
        for (int fc = 0; fc < 4; ++fc)
            acc[fr][fc] = (f32x4){0.f, 0.f, 0.f, 0.f};

    for (int ks = 0; ks < 36; ++ks) {
        int i0 = ks * 8 + (t & 3) * 2;            // two items per 8-bf16 chunk
        int i1 = i0 + 1;
        int n0 = i0 / 9, kl0 = i0 % 9;
        int n1 = i1 / 9, kl1 = i1 % 9;
        int o0 = n0 * 4096 + (kl0 / 3) * 256 + (kl0 % 3) * 16;
        int o1 = n1 * 4096 + (kl1 / 3) * 256 + (kl1 % 3) * 16;
        uint4 a0 = pack_bf16_8(*(const float4*)(vbase[0] + o0),
                               *(const float4*)(vbase[0] + o1));
        uint4 a1 = pack_bf16_8(*(const float4*)(vbase[1] + o0),
                               *(const float4*)(vbase[1] + o1));
        uint4 b0 = *(const uint4*)(wsrc + ks * 32);
        __syncthreads();
        *(uint4*)&sA[(unsigned)t * 8]         = a0;
        *(uint4*)&sA[((unsigned)t + 256) * 8] = a1;
        *(uint4*)&sB[(unsigned)t * 8]         = b0;
        __syncthreads();

        Frag af0, af1, bf[4];
        af0.s = *(const short8*)&sA[(wid * 32 + lo) * 32 + hi * 8];
        af1.s = *(const short8*)&sA[(wid * 32 + 16 + lo) * 32 + hi * 8];
        #pragma unroll
        for (int fc = 0; fc < 4; ++fc)
            bf[fc].s = *(const short8*)&sB[(fc * 16 + lo) * 32 + hi * 8];
        #pragma unroll
        for (int fc = 0; fc < 4; ++fc) {
            acc[0][fc] = __builtin_amdgcn_mfma_f32_16x16x32_bf16(
                af0.b, bf[fc].b, acc[0][fc], 0, 0, 0);
            acc[1][fc] = __builtin_amdgcn_mfma_f32_16x16x32_bf16(
                af1.b, bf[fc].b, acc[1][fc], 0, 0, 0);
        }
    }

    #pragma unroll
    for (int fr = 0; fr < 2; ++fr)
        #pragma unroll
        for (int fc = 0; fc < 4; ++fc)
            #pragma unroll
            for (int j = 0; j < 4; ++j) {
                int row = pbase + wid * 32 + fr * 16 + hi * 4 + j;
                int col = ocbase + fc * 16 + lo;
                nv1g[row * 128 + col] = acc[fr][fc][j];
            }
}

// ===================== caps routing pass 2 + LN1 (pass 1 via k_nv1_mfma) =====================
__global__ __launch_bounds__(256) void k_capsfused(const float* __restrict__ val,
                                                   const __bf16* __restrict__ cw2,
                                                   const float* __restrict__ nv1g,
                                                   const float* __restrict__ g,
                                                   const float* __restrict__ bt,
                                                   float* __restrict__ vout) {
    int bb = blockIdx.x / 49;
    int hw = blockIdx.x % 49;
    int h = hw / 7, w = hw % 7;

    __shared__ uint4 ulocH[2][576];     // 18432 B; aliased by wred after loop
    __shared__ float v1s[2][512];       //  4096 B  nv2 scratch
    float* wred = (float*)ulocH;        //  8704 B needed <= 18432

    for (int t = threadIdx.x; t < 1152; t += 256) {
        int s = t / 576, tt = t % 576;
        int item = tt >> 1, hf = tt & 1;
        int n = item / 9, kl = item % 9;
        int k = kl / 3, l = kl % 3;
        int b = bb + s * 32;
        const float4* src = (const float4*)(val +
            (((b * 32 + n) * 16 + (2 * h + k)) * 16 + (2 * w + l)) * 16 + hf * 8);
        ulocH[s][tt] = pack_bf16_8(src[0], src[1]);
    }

    const int lane  = threadIdx.x & 31;          // m
    const int grpid = threadIdx.x >> 5;          // 0..7
    const int wid   = threadIdx.x >> 6;          // 0..3
    const bool half0 = (threadIdx.x & 32) == 0;

    // nvp from nv1 GEMM: /32 + lane-local LN
    float nvp[2][16];
    #pragma unroll
    for (int s = 0; s < 2; ++s) {
        int site = (bb + s * 32) * 49 + hw;
        #pragma unroll
        for (int a = 0; a < 4; ++a) {
            float4 q = *(const float4*)(nv1g + (site * 4 + a) * 128 + lane * 4);
            nvp[s][a * 4 + 0] = q.x * (1.f / 32.f);
            nvp[s][a * 4 + 1] = q.y * (1.f / 32.f);
            nvp[s][a * 4 + 2] = q.z * (1.f / 32.f);
            nvp[s][a * 4 + 3] = q.w * (1.f / 32.f);
        }
        float mu = 0.f;
        #pragma unroll
        for (int j = 0; j < 16; ++j) mu += nvp[s][j];
        mu *= (1.f / 16.f);
        float var = 0.f;
        #pragma unroll
        for (int j = 0; j < 16; ++j) { float d = nvp[s][j] - mu; var += d * d; }
        var *= (1.f / 16.f);
        float rs = rsqrtf(var + EPSLN);
        #pragma unroll
        for (int j = 0; j < 16; ++j)
            nvp[s][j] = (nvp[s][j] - mu) * rs * g[j] + bt[j];
    }

    float nvacc[2][16];
    #pragma unroll
    for (int s = 0; s < 2; ++s)
        #pragma unroll
        for (int j = 0; j < 16; ++j) nvacc[s][j] = 0.f;

    __syncthreads();

    // ---------------- pass 2: routed ----------------
    {
        uint4 wq0, wq1;
        {
            int n = grpid / 9, kl = grpid % 9;
            const uint4* wb = (const uint4*)(cw2 + (((kl * 32 + n) * 32) + lane) * 16);
            wq0 = wb[0]; wq1 = wb[1];
        }
        for (int it = grpid; it < 288; it += 8) {
            int nit = it + 8;
            uint4 nq0 = wq0, nq1 = wq1;
            if (nit < 288) {
                int n = nit / 9, kl = nit % 9;
                const uint4* wb = (const uint4*)(cw2 + (((kl * 32 + n) * 32) + lane) * 16);
                nq0 = wb[0]; nq1 = wb[1];
            }
            float cwv[16];
            {
                union { uint4 u; __bf16 hh[8]; } qa, qb;
                qa.u = wq0; qb.u = wq1;
                #pragma unroll
                for (int j = 0; j < 8; ++j) {
                    cwv[j] = (float)qa.hh[j]; cwv[8 + j] = (float)qb.hh[j];
                }
            }
            #pragma unroll
            for (int s = 0; s < 2; ++s) {
                union { uint4 u; __bf16 hh[8]; } q0, q1;
                q0.u = ulocH[s][it * 2];
                q1.u = ulocH[s][it * 2 + 1];
                float u16[16];
                #pragma unroll
                for (int j = 0; j < 8; ++j) { u16[j] = (float)q0.hh[j]; u16[8 + j] = (float)q1.hh[j]; }
                float votes[16];
                #pragma unroll
                for (int a = 0; a < 4; ++a)
                    #pragma unroll
                    for (int d = 0; d < 4; ++d) {
                        float v = 0.f;
                        #pragma unroll
                        for (int x = 0; x < 4; ++x)
                            v = fmaf(u16[a * 4 + x], cwv[x * 4 + d], v);
                        votes[a * 4 + d] = v;
                    }
                float qk = 0.f;
                #pragma unroll
                for (int j = 0; j < 16; ++j) qk = fmaf(votes[j], nvp[s][j], qk);
                qk *= 0.25f;                          // 1/sqrt(16)
                float e = __expf(fminf(fmaxf(qk, -30.f), 30.f));
                float sm = e;
                #pragma unroll
                for (int off = 1; off < 32; off <<= 1) sm += __shfl_xor(sm, off);
                float qv = e / sm;
                #pragma unroll
                for (int j = 0; j < 16; ++j) nvacc[s][j] = fmaf(qv, votes[j], nvacc[s][j]);
            }
            wq0 = nq0; wq1 = nq1;
        }
    }

    // reduce -> nv2 -> LN -> global  (wred aliases ulocH; barrier-separated)
    #pragma unroll
    for (int s = 0; s < 2; ++s)
        #pragma unroll
        for (int j = 0; j < 16; ++j)
            nvacc[s][j] += __shfl_xor(nvacc[s][j], 32);
    #pragma unroll
    for (int s = 0; s < 2; ++s) {
        __syncthreads();
        if (half0) {
            #pragma unroll
            for (int j = 0; j < 16; ++j) wred[wid * 544 + lane * 17 + j] = nvacc[s][j];
        }
        __syncthreads();
        for (int o = threadIdx.x; o < 512; o += 256) {
            int mm = o >> 4, j = o & 15;
            float sum = wred[0 * 544 + mm * 17 + j] + wred[1 * 544 + mm * 17 + j]
                      + wred[2 * 544 + mm * 17 + j] + wred[3 * 544 + mm * 17 + j];
            v1s[s][o] = sum;
        }
    }
    __syncthreads();
    if (threadIdx.x < 64) {
        int s = threadIdx.x >> 5, m = threadIdx.x & 31;
        int b = bb + s * 32;
        float v16[16], mu = 0.f;
        #pragma unroll
        for (int j = 0; j < 16; ++j) { v16[j] = v1s[s][m * 16 + j]; mu += v16[j]; }
        mu *= (1.f / 16.f);
        float var = 0.f;
        #pragma unroll
        for (int j = 0; j < 16; ++j) { float t = v16[j] - mu; var += t * t; }
        var *= (1.f / 16.f);
        float rs = rsqrtf(var + EPSLN);
        float o16[16];
        #pragma unroll
        for (int j = 0; j < 16; ++j) o16[j] = (v16[j] - mu) * rs * g[j] + bt[j];
        float4* dst = (float4*)(vout + (((b * 32 + m) * 7 + h) * 7 + w) * 16);
        dst[0] = make_float4(o16[0],  o16[1],  o16[2],  o16[3]);
        dst[1] = make_float4(o16[4],  o16[5],  o16[6],  o16[7]);
        dst[2] = make_float4(o16[8],  o16[9],  o16[10], o16[11]);
        dst[3] = make_float4(o16[12], o16[13], o16[14], o16[15]);
    }
}

// ===================== fc step1 + LN2: v2 -> p =====================
__global__ __launch_bounds__(256) void k_fc1(const float* __restrict__ fin,
                                             const float* __restrict__ fwp,
                                             const float* __restrict__ g,
                                             const float* __restrict__ bt,
                                             float* __restrict__ p) {
    int b = blockIdx.x / 10, m = blockIdx.x % 10;
    const float* fb = fin + b * 1568 * 16;
    const float* wb = fwp + m * 1568 * 16;
    float acc[16];
    #pragma unroll
    for (int j = 0; j < 16; ++j) acc[j] = 0.f;

    for (int n = threadIdx.x; n < 1568; n += 256) {
        const float4* u4 = (const float4*)(fb + n * 16);
        const float4* w4 = (const float4*)(wb + n * 16);
        float u16[16], w16[16];
        #pragma unroll
        for (int f = 0; f < 4; ++f) {
            float4 a = u4[f], bq = w4[f];
            u16[f * 4 + 0] = a.x;  u16[f * 4 + 1] = a.y;
            u16[f * 4 + 2] = a.z;  u16[f * 4 + 3] = a.w;
            w16[f * 4 + 0] = bq.x; w16[f * 4 + 1] = bq.y;
            w16[f * 4 + 2] = bq.z; w16[f * 4 + 3] = bq.w;
        }
        #pragma unroll
        for (int a = 0; a < 4; ++a)
            #pragma unroll
            for (int d = 0; d < 4; ++d) {
                float s = acc[a * 4 + d];
                #pragma unroll
                for (int x = 0; x < 4; ++x)
                    s = fmaf(u16[a * 4 + x], w16[x * 4 + d], s);
                acc[a * 4 + d] = s;
            }
    }
    #pragma unroll
    for (int j = 0; j < 16; ++j)
        #pragma unroll
        for (int off = 1; off < 64; off <<= 1)
            acc[j] += __shfl_xor(acc[j], off);

    __shared__ float red[4][16];
    int wid = threadIdx.x >> 6, ln = threadIdx.x & 63;
    if (ln == 0) {
        #pragma unroll
        for (int j = 0; j < 16; ++j) red[wid][j] = acc[j];
    }
    __syncthreads();
    if (threadIdx.x < 16) {
        int j = threadIdx.x;
        float s = (red[0][j] + red[1][j] + red[2][j] + red[3][j]) * 0.1f;
        float mu = s;
        #pragma unroll
        for (int off = 1; off < 16; off <<= 1) mu += __shfl_xor(mu, off);
        mu *= (1.f / 16.f);
        float t = s - mu;
        float var = t * t;
        #pragma unroll
        for (int off = 1; off < 16; off <<= 1) var += __shfl_xor(var, off);
        var *= (1.f / 16.f);
        float rs = rsqrtf(var + EPSLN);
        p[(b * 10 + m) * 16 + j] = t * rs * g[j] + bt[j];
    }
}

// ===================== fc routing + LN2: v2,p -> out =====================
__global__ __launch_bounds__(256) void k_fc2(const float* __restrict__ fin,
                                             const float* __restrict__ fw,
                                             const float* __restrict__ p,
                                             const float* __restrict__ g,
                                             const float* __restrict__ bt,
                                             float* __restrict__ out) {
    int b = blockIdx.x;
    int ad    = threadIdx.x & 15;
    int grpid = threadIdx.x >> 4;
    int a = ad >> 2, d = ad & 3;

    float pv[10];
    #pragma unroll
    for (int m = 0; m < 10; ++m) pv[m] = p[(b * 10 + m) * 16 + ad];

    float acc[10];
    #pragma unroll
    for (int m = 0; m < 10; ++m) acc[m] = 0.f;

    const float* fb = fin + b * 1568 * 16;
    for (int n = grpid; n < 1568; n += 16) {
        float4 u4 = *(const float4*)(fb + n * 16 + a * 4);
        const float* wb = fw + n * 160 + d * 10;
        float votes[10];
        #pragma unroll
        for (int m = 0; m < 10; ++m)
            votes[m] = u4.x * wb[m] + u4.y * wb[40 + m] +
                       u4.z * wb[80 + m] + u4.w * wb[120 + m];
        float qk[10];
        #pragma unroll
        for (int m = 0; m < 10; ++m) {
            float t = votes[m] * pv[m];
            #pragma unroll
            for (int off = 1; off < 16; off <<= 1) t += __shfl_xor(t, off);
            qk[m] = t * 0.25f;
        }
        float mx = qk[0];
        #pragma unroll
        for (int m = 1; m < 10; ++m) mx = fmaxf(mx, qk[m]);
        float e[10], s = 0.f;
        #pragma unroll
        for (int m = 0; m < 10; ++m) { e[m] = __expf(qk[m] - mx); s += e[m]; }
        float inv = 1.f / s;
        #pragma unroll
        for (int m = 0; m < 10; ++m) acc[m] = fmaf(e[m] * inv, votes[m], acc[m]);
    }

    __shared__ float red[16][16][10];
    #pragma unroll
    for (int m = 0; m < 10; ++m) red[grpid][ad][m] = acc[m];
    __syncthreads();

    if (threadIdx.x < 160) {
        int m = threadIdx.x / 16, j = threadIdx.x % 16;
        float s = 0.f;
        #pragma unroll
        for (int gg = 0; gg < 16; ++gg) s += red[gg][j][m];
        float mu = s;
        #pragma unroll
        for (int off = 1; off < 16; off <<= 1) mu += __shfl_xor(mu, off);
        mu *= (1.f / 16.f);
        float t = s - mu;
        float var = t * t;
        #pragma unroll
        for (int off = 1; off < 16; off <<= 1) var += __shfl_xor(var, off);
        var *= (1.f / 16.f);
        float rs = rsqrtf(var + EPSLN);
        out[(b * 10 + m) * 16 + j] = t * rs * g[j] + bt[j];
    }
}

// ============================ launch ============================
extern "C" void kernel_launch(void* const* d_in, const int* in_sizes, int n_in,
                              void* d_out, int out_size, void* d_ws, size_t ws_size,
                              hipStream_t stream) {
    const float* x    = (const float*)d_in[0];
    const float* bbw  = (const float*)d_in[1];
    const float* bbb  = (const float*)d_in[2];
    const float* pcw  = (const float*)d_in[3];
    const float* ln0g = (const float*)d_in[4];
    const float* ln0b = (const float*)d_in[5];
    const float* cwt  = (const float*)d_in[6];
    const float* ln1g = (const float*)d_in[7];
    const float* ln1b = (const float*)d_in[8];
    const float* fw   = (const float*)d_in[9];
    const float* ln2g = (const float*)d_in[10];
    const float* ln2b = (const float*)d_in[11];
    float* outp = (float*)d_out;

    // Workspace layout (f32 units) -- every extent re-derived:
    //   c2p : 64*34*34*128 bf16 = 9,469,952 bf16 = 4,734,976 f32
    //   wbT : 589,824 bf16 = 294,912 f32
    //   bwT : 3,456
    //   val : 64*512*16*16 = 8,388,608
    //   v2  : 64*32*7*7*16 = 1,605,632
    //   fwp : 250,880
    //   p   : 10,240
    //   cw2 : 147,456 bf16 = 73,728 f32   (R10 bug: had 36,864)
    //   cwB : 147,456 bf16 = 73,728 f32
    //   nv1g: 12544*128    = 1,605,632
    float* ws = (float*)d_ws;
    __bf16* c2p  = (__bf16*)ws;                 // [0,          4,734,976)
    __bf16* wbT  = (__bf16*)(ws + 4734976);     // [4,734,976,  5,029,888)
    float*  bwT  = ws + 5029888;                // [5,029,888,  5,033,344)
    float*  val  = ws + 5033344;                // [5,033,344, 13,421,952)
    float*  v2   = ws + 13421952;               // [13,421,952, 15,027,584)
    float*  fwp  = ws + 15027584;               // [15,027,584, 15,278,464)
    float*  p    = ws + 15278464;               // [15,278,464, 15,288,704)
    __bf16* cw2  = (__bf16*)(ws + 15288704);    // [15,288,704, 15,362,432)
    __bf16* cwB  = (__bf16*)(ws + 15362432);    // [15,362,432, 15,436,160)
    float*  nv1g = ws + 15436160;               // [15,436,160, 17,041,792) ~68.2 MB

    hipMemsetAsync(c2p, 0, (size_t)9469952 * 2, stream);
    k_repack_bw  <<<14,   256, 0, stream>>>(bbw, bwT);
    k_repack_pcw <<<2304, 256, 0, stream>>>(pcw, wbT);
    k_repack_fw  <<<980,  256, 0, stream>>>(fw, fwp);
    k_repack_cw2 <<<576,  256, 0, stream>>>(cwt, cw2);
    k_repack_cwB <<<576,  256, 0, stream>>>(cwt, cwB);
    k_conv1      <<<32768, 256, 0, stream>>>(x, bwT, bbb, c2p);
    k_conv2_mfma <<<1024, 256, 0, stream>>>(c2p, wbT, ln0g, ln0b, val);
    k_nv1_mfma   <<<196,  256, 0, stream>>>(val, cwB, nv1g);
    k_capsfused  <<<1568, 256, 0, stream>>>(val, cw2, nv1g, ln1g, ln1b, v2);
    k_fc1        <<<640, 256, 0, stream>>>(v2, fwp, ln2g, ln2b, p);
    k_fc2        <<<64, 256, 0, stream>>>(v2, fw, p, ln2g, ln2b, outp);
}

// Round 12
// 334.460 us; speedup vs baseline: 1.7177x; 1.3423x over previous
//
#include <hip/hip_runtime.h>

// CapsTimeModel forward, round 12: non-capsfused sweep.
//   - conv2/nv1: software-pipelined (prefetch ks+1 loads before MFMA of ks)
//   - fc2: 1024-thread blocks (64 n-groups; was 16 -> 4x parallelism)
//   - conv1: 4 oc per thread (float4 weights, 8B bf16x4 stores)
//   - 5 repack kernels fused into k_repack_all (blockIdx-range dispatch)
// capsfused / fc1 / workspace layout identical to R11 (passing, 449us).

#define EPSLN 1e-5f

typedef short  short8 __attribute__((ext_vector_type(8)));
typedef __bf16 bf16x8 __attribute__((ext_vector_type(8)));
typedef float  f32x4  __attribute__((ext_vector_type(4)));

union Frag { short8 s; bf16x8 b; };

__device__ __forceinline__ uint4 pack_bf16_8(float4 a, float4 b) {
    union { __bf16 h[8]; uint4 u; } r;
    r.h[0] = (__bf16)a.x; r.h[1] = (__bf16)a.y;
    r.h[2] = (__bf16)a.z; r.h[3] = (__bf16)a.w;
    r.h[4] = (__bf16)b.x; r.h[5] = (__bf16)b.y;
    r.h[6] = (__bf16)b.z; r.h[7] = (__bf16)b.w;
    return r.u;
}

// ==================== fused repacks (blockIdx-range dispatch) ====================
__global__ __launch_bounds__(256) void k_repack_all(
        const float* __restrict__ bw,  float* __restrict__ bwT,
        const float* __restrict__ pw,  __bf16* __restrict__ wbT,
        const float* __restrict__ fw,  float* __restrict__ fwp,
        const float* __restrict__ cw,  __bf16* __restrict__ cw2,
        __bf16* __restrict__ cwB) {
    int blk = blockIdx.x;
    if (blk < 2304) {                         // pcw -> wbT : 589824 exact
        int i = blk * 256 + threadIdx.x;
        int oc = i / 1152, r = i % 1152;
        int ic = r / 9, tap = r % 9;
        wbT[oc * 1152 + tap * 128 + ic] = (__bf16)pw[i];
    } else if (blk < 3284) {                  // fw -> fwp : 250880 exact
        int i = (blk - 2304) * 256 + threadIdx.x;
        int m = i % 10;
        int d = (i / 10) & 3;
        int x = (i / 40) & 3;
        int n = i / 160;
        fwp[(m * 1568 + n) * 16 + x * 4 + d] = fw[i];
    } else if (blk < 3860) {                  // cw -> cw2 : 147456 exact
        int i = (blk - 3284) * 256 + threadIdx.x;
        int m  = i & 31;
        int d  = (i >> 5) & 3;
        int x  = (i >> 7) & 3;
        int n  = (i >> 9) & 31;
        int kl = i >> 14;
        cw2[(((kl * 32 + n) * 32) + m) * 16 + x * 4 + d] = (__bf16)cw[i];
    } else if (blk < 4436) {                  // cw -> cwB : 147456 exact
        int i = (blk - 3860) * 256 + threadIdx.x;
        int m  = i & 31;
        int d  = (i >> 5) & 3;
        int x  = (i >> 7) & 3;
        int n  = (i >> 9) & 31;
        int kl = i >> 14;
        cwB[(m * 4 + d) * 1152 + (n * 9 + kl) * 4 + x] = (__bf16)cw[i];
    } else {                                  // bw -> bwT : 3456
        int i = (blk - 4436) * 256 + threadIdx.x;
        if (i < 3456) {
            int oc = i / 27, r = i % 27;
            bwT[r * 128 + oc] = bw[i];
        }
    }
}

// ==================== conv1: x -> c2p (NHWC bf16, padded), 4 oc/thread ====================
__global__ __launch_bounds__(256) void k_conv1(const float* __restrict__ x,
                                               const float* __restrict__ bwT,
                                               const float* __restrict__ bb,
                                               __bf16* __restrict__ c2p) {
    int gid = blockIdx.x * 256 + threadIdx.x;     // 2,097,152 (=64*32*32*32)
    int oc4 = gid & 31;
    int p   = gid >> 5;
    int w = p & 31, h = (p >> 5) & 31, b = p >> 10;
    const float* xb = x + b * 12288;
    float4 acc = *(const float4*)(bb + oc4 * 4);
    #pragma unroll
    for (int ky = 0; ky < 3; ++ky) {
        int ih = 2 * h + ky - 1;
        if ((unsigned)ih >= 64u) continue;
        #pragma unroll
        for (int kx = 0; kx < 3; ++kx) {
            int iw = 2 * w + kx - 1;
            if ((unsigned)iw >= 64u) continue;
            #pragma unroll
            for (int ic = 0; ic < 3; ++ic) {
                float in = xb[(ic * 64 + ih) * 64 + iw];
                float4 wv = *(const float4*)(bwT + (ic * 9 + ky * 3 + kx) * 128 + oc4 * 4);
                acc.x = fmaf(in, wv.x, acc.x);
                acc.y = fmaf(in, wv.y, acc.y);
                acc.z = fmaf(in, wv.z, acc.z);
                acc.w = fmaf(in, wv.w, acc.w);
            }
        }
    }
    union { __bf16 h4[4]; unsigned long long ull; } r;
    r.h4[0] = (__bf16)fmaxf(acc.x, 0.f);
    r.h4[1] = (__bf16)fmaxf(acc.y, 0.f);
    r.h4[2] = (__bf16)fmaxf(acc.z, 0.f);
    r.h4[3] = (__bf16)fmaxf(acc.w, 0.f);
    *(unsigned long long*)(c2p + ((b * 34 + h + 1) * 34 + (w + 1)) * 128 + oc4 * 4) = r.ull;
}

// ==================== conv2: pipelined MFMA GEMM + fused LN0 -> val ====================
__global__ __launch_bounds__(256) void k_conv2_mfma(const __bf16* __restrict__ c2p,
                                                    const __bf16* __restrict__ wbT,
                                                    const float* __restrict__ g,
                                                    const float* __restrict__ bt,
                                                    float* __restrict__ val) {
    __shared__ unsigned short sA[128 * 32];
    __shared__ unsigned short sB[64 * 32];

    const int t = threadIdx.x;
    const int mblk = blockIdx.x >> 3, nblk = blockIdx.x & 7;
    const int pbase = mblk * 128, ocbase = nblk * 64;
    const int b = pbase >> 8;

    const int r0 = t >> 2, r1 = r0 + 64;
    const int kc8 = (t & 3) * 8;
    const int oh0 = ((pbase + r0) >> 4) & 15, ow0 = (pbase + r0) & 15;
    const int oh1 = ((pbase + r1) >> 4) & 15, ow1 = (pbase + r1) & 15;

    const unsigned short* cb = (const unsigned short*)c2p + (size_t)b * 147968;
    const unsigned short* ws = (const unsigned short*)wbT
                               + (ocbase + (t >> 2)) * 1152 + kc8;

    const int lane = t & 63, wid = t >> 6;
    const int lo = lane & 15, hi = lane >> 4;

    f32x4 acc[2][4];
    #pragma unroll
    for (int fr = 0; fr < 2; ++fr)
        #pragma unroll
        for (int fc = 0; fc < 4; ++fc)
            acc[fr][fc] = (f32x4){0.f, 0.f, 0.f, 0.f};

    // prologue: stage ks=0 (tap 0, ic0 0)
    {
        uint4 a0 = *(const uint4*)(cb + ((2 * oh0) * 34 + 2 * ow0) * 128 + kc8);
        uint4 a1 = *(const uint4*)(cb + ((2 * oh1) * 34 + 2 * ow1) * 128 + kc8);
        uint4 b0 = *(const uint4*)(ws);
        *(uint4*)&sA[(unsigned)t * 8]         = a0;
        *(uint4*)&sA[((unsigned)t + 256) * 8] = a1;
        *(uint4*)&sB[(unsigned)t * 8]         = b0;
        __syncthreads();
    }

    for (int ks = 0; ks < 36; ++ks) {
        uint4 a0, a1, b0;
        const bool pre = (ks + 1) < 36;
        if (pre) {
            int ksn = ks + 1;
            int tap = ksn / 4, ic0 = (ksn % 4) * 32;
            int ty = tap / 3, tx = tap % 3;
            a0 = *(const uint4*)(cb + ((2 * oh0 + ty) * 34 + (2 * ow0 + tx)) * 128
                                    + ic0 + kc8);
            a1 = *(const uint4*)(cb + ((2 * oh1 + ty) * 34 + (2 * ow1 + tx)) * 128
                                    + ic0 + kc8);
            b0 = *(const uint4*)(ws + ksn * 32);
        }
        Frag af0, af1, bf[4];
        af0.s = *(const short8*)&sA[(wid * 32 + lo) * 32 + hi * 8];
        af1.s = *(const short8*)&sA[(wid * 32 + 16 + lo) * 32 + hi * 8];
        #pragma unroll
        for (int fc = 0; fc < 4; ++fc)
            bf[fc].s = *(const short8*)&sB[(fc * 16 + lo) * 32 + hi * 8];
        #pragma unroll
        for (int fc = 0; fc < 4; ++fc) {
            acc[0][fc] = __builtin_amdgcn_mfma_f32_16x16x32_bf16(
                af0.b, bf[fc].b, acc[0][fc], 0, 0, 0);
            acc[1][fc] = __builtin_amdgcn_mfma_f32_16x16x32_bf16(
                af1.b, bf[fc].b, acc[1][fc], 0, 0, 0);
        }
        __syncthreads();
        if (pre) {
            *(uint4*)&sA[(unsigned)t * 8]         = a0;
            *(uint4*)&sA[((unsigned)t + 256) * 8] = a1;
            *(uint4*)&sB[(unsigned)t * 8]         = b0;
        }
        __syncthreads();
    }

    const float gv = g[lo], bv = bt[lo];
    #pragma unroll
    for (int fr = 0; fr < 2; ++fr) {
        #pragma unroll
        for (int fc = 0; fc < 4; ++fc) {
            const int n = (ocbase >> 4) + fc;
            #pragma unroll
            for (int j = 0; j < 4; ++j) {
                float v = acc[fr][fc][j];
                float s1 = v, s2 = v * v;
                #pragma unroll
                for (int off = 1; off < 16; off <<= 1) {
                    s1 += __shfl_xor(s1, off);
                    s2 += __shfl_xor(s2, off);
                }
                float mu  = s1 * (1.f / 16.f);
                float var = s2 * (1.f / 16.f) - mu * mu;
                float rs  = rsqrtf(var + EPSLN);
                float o   = (v - mu) * rs * gv + bv;
                int p  = pbase + wid * 32 + fr * 16 + hi * 4 + j;
                int oh = (p >> 4) & 15, ow = p & 15;
                val[(((b * 32 + n) * 16 + oh) * 16 + ow) * 16 + lo] = o;
            }
        }
    }
}

// ==================== nv1 GEMM (pipelined): val x cwB -> nv1g ====================
__global__ __launch_bounds__(256) void k_nv1_mfma(const float* __restrict__ val,
                                                  const __bf16* __restrict__ cwB,
                                                  float* __restrict__ nv1g) {
    __shared__ unsigned short sA[128 * 32];
    __shared__ unsigned short sB[64 * 32];

    const int t = threadIdx.x;
    const int mblk = blockIdx.x >> 1, nblk = blockIdx.x & 1;
    const int pbase = mblk * 128, ocbase = nblk * 64;

    const float* vbase[2];
    #pragma unroll
    for (int u = 0; u < 2; ++u) {
        int r = pbase + (t >> 2) + u * 64;
        int site = r >> 2, a = r & 3;
        int b = site / 49, hw = site % 49;
        int h = hw / 7, w = hw % 7;
        vbase[u] = val + (size_t)b * 131072 + (2 * h) * 256 + (2 * w) * 16 + a * 4;
    }
    const unsigned short* wsrc = (const unsigned short*)cwB
                                 + (ocbase + (t >> 2)) * 1152 + (t & 3) * 8;

    const int lane = t & 63, wid = t >> 6;
    const int lo = lane & 15, hi = lane >> 4;

    f32x4 acc[2][4];
    #pragma unroll
    for (int fr = 0; fr < 2; ++fr)
        #pragma unroll
        for (int fc = 0; fc < 4; ++fc)
            acc[fr][fc] = (f32x4){0.f, 0.f, 0.f, 0.f};

    auto itemoff = [](int i) {
        int n = i / 9, kl = i % 9;
        return n * 4096 + (kl / 3) * 256 + (kl % 3) * 16;
    };

    // prologue: stage ks=0
    {
        int i0 = (t & 3) * 2;
        int o0 = itemoff(i0), o1 = itemoff(i0 + 1);
        uint4 a0 = pack_bf16_8(*(const float4*)(vbase[0] + o0),
                               *(const float4*)(vbase[0] + o1));
        uint4 a1 = pack_bf16_8(*(const float4*)(vbase[1] + o0),
                               *(const float4*)(vbase[1] + o1));
        uint4 b0 = *(const uint4*)(wsrc);
        *(uint4*)&sA[(unsigned)t * 8]         = a0;
        *(uint4*)&sA[((unsigned)t + 256) * 8] = a1;
        *(uint4*)&sB[(unsigned)t * 8]         = b0;
        __syncthreads();
    }

    for (int ks = 0; ks < 36; ++ks) {
        uint4 a0, a1, b0;
        const bool pre = (ks + 1) < 36;
        if (pre) {
            int i0 = (ks + 1) * 8 + (t & 3) * 2;
            int o0 = itemoff(i0), o1 = itemoff(i0 + 1);
            a0 = pack_bf16_8(*(const float4*)(vbase[0] + o0),
                             *(const float4*)(vbase[0] + o1));
            a1 = pack_bf16_8(*(const float4*)(vbase[1] + o0),
                             *(const float4*)(vbase[1] + o1));
            b0 = *(const uint4*)(wsrc + (ks + 1) * 32);
        }
        Frag af0, af1, bf[4];
        af0.s = *(const short8*)&sA[(wid * 32 + lo) * 32 + hi * 8];
        af1.s = *(const short8*)&sA[(wid * 32 + 16 + lo) * 32 + hi * 8];
        #pragma unroll
        for (int fc = 0; fc < 4; ++fc)
            bf[fc].s = *(const short8*)&sB[(fc * 16 + lo) * 32 + hi * 8];
        #pragma unroll
        for (int fc = 0; fc < 4; ++fc) {
            acc[0][fc] = __builtin_amdgcn_mfma_f32_16x16x32_bf16(
                af0.b, bf[fc].b, acc[0][fc], 0, 0, 0);
            acc[1][fc] = __builtin_amdgcn_mfma_f32_16x16x32_bf16(
                af1.b, bf[fc].b, acc[1][fc], 0, 0, 0);
        }
        __syncthreads();
        if (pre) {
            *(uint4*)&sA[(unsigned)t * 8]         = a0;
            *(uint4*)&sA[((unsigned)t + 256) * 8] = a1;
            *(uint4*)&sB[(unsigned)t * 8]         = b0;
        }
        __syncthreads();
    }

    #pragma unroll
    for (int fr = 0; fr < 2; ++fr)
        #pragma unroll
        for (int fc = 0; fc < 4; ++fc)
            #pragma unroll
            for (int j = 0; j < 4; ++j) {
                int row = pbase + wid * 32 + fr * 16 + hi * 4 + j;
                int col = ocbase + fc * 16 + lo;
                nv1g[row * 128 + col] = acc[fr][fc][j];
            }
}

// ===================== caps routing pass 2 + LN1 (pass 1 via k_nv1_mfma) =====================
__global__ __launch_bounds__(256) void k_capsfused(const float* __restrict__ val,
                                                   const __bf16* __restrict__ cw2,
                                                   const float* __restrict__ nv1g,
                                                   const float* __restrict__ g,
                                                   const float* __restrict__ bt,
                                                   float* __restrict__ vout) {
    int bb = blockIdx.x / 49;
    int hw = blockIdx.x % 49;
    int h = hw / 7, w = hw % 7;

    __shared__ uint4 ulocH[2][576];     // 18432 B; aliased by wred after loop
    __shared__ float v1s[2][512];       //  4096 B  nv2 scratch
    float* wred = (float*)ulocH;        //  8704 B needed <= 18432

    for (int t = threadIdx.x; t < 1152; t += 256) {
        int s = t / 576, tt = t % 576;
        int item = tt >> 1, hf = tt & 1;
        int n = item / 9, kl = item % 9;
        int k = kl / 3, l = kl % 3;
        int b = bb + s * 32;
        const float4* src = (const float4*)(val +
            (((b * 32 + n) * 16 + (2 * h + k)) * 16 + (2 * w + l)) * 16 + hf * 8);
        ulocH[s][tt] = pack_bf16_8(src[0], src[1]);
    }

    const int lane  = threadIdx.x & 31;          // m
    const int grpid = threadIdx.x >> 5;          // 0..7
    const int wid   = threadIdx.x >> 6;          // 0..3
    const bool half0 = (threadIdx.x & 32) == 0;

    // nvp from nv1 GEMM: /32 + lane-local LN
    float nvp[2][16];
    #pragma unroll
    for (int s = 0; s < 2; ++s) {
        int site = (bb + s * 32) * 49 + hw;
        #pragma unroll
        for (int a = 0; a < 4; ++a) {
            float4 q = *(const float4*)(nv1g + (site * 4 + a) * 128 + lane * 4);
            nvp[s][a * 4 + 0] = q.x * (1.f / 32.f);
            nvp[s][a * 4 + 1] = q.y * (1.f / 32.f);
            nvp[s][a * 4 + 2] = q.z * (1.f / 32.f);
            nvp[s][a * 4 + 3] = q.w * (1.f / 32.f);
        }
        float mu = 0.f;
        #pragma unroll
        for (int j = 0; j < 16; ++j) mu += nvp[s][j];
        mu *= (1.f / 16.f);
        float var = 0.f;
        #pragma unroll
        for (int j = 0; j < 16; ++j) { float d = nvp[s][j] - mu; var += d * d; }
        var *= (1.f / 16.f);
        float rs = rsqrtf(var + EPSLN);
        #pragma unroll
        for (int j = 0; j < 16; ++j)
            nvp[s][j] = (nvp[s][j] - mu) * rs * g[j] + bt[j];
    }

    float nvacc[2][16];
    #pragma unroll
    for (int s = 0; s < 2; ++s)
        #pragma unroll
        for (int j = 0; j < 16; ++j) nvacc[s][j] = 0.f;

    __syncthreads();

    // ---------------- pass 2: routed ----------------
    {
        uint4 wq0, wq1;
        {
            int n = grpid / 9, kl = grpid % 9;
            const uint4* wb = (const uint4*)(cw2 + (((kl * 32 + n) * 32) + lane) * 16);
            wq0 = wb[0]; wq1 = wb[1];
        }
        for (int it = grpid; it < 288; it += 8) {
            int nit = it + 8;
            uint4 nq0 = wq0, nq1 = wq1;
            if (nit < 288) {
                int n = nit / 9, kl = nit % 9;
                const uint4* wb = (const uint4*)(cw2 + (((kl * 32 + n) * 32) + lane) * 16);
                nq0 = wb[0]; nq1 = wb[1];
            }
            float cwv[16];
            {
                union { uint4 u; __bf16 hh[8]; } qa, qb;
                qa.u = wq0; qb.u = wq1;
                #pragma unroll
                for (int j = 0; j < 8; ++j) {
                    cwv[j] = (float)qa.hh[j]; cwv[8 + j] = (float)qb.hh[j];
                }
            }
            #pragma unroll
            for (int s = 0; s < 2; ++s) {
                union { uint4 u; __bf16 hh[8]; } q0, q1;
                q0.u = ulocH[s][it * 2];
                q1.u = ulocH[s][it * 2 + 1];
                float u16[16];
                #pragma unroll
                for (int j = 0; j < 8; ++j) { u16[j] = (float)q0.hh[j]; u16[8 + j] = (float)q1.hh[j]; }
                float votes[16];
                #pragma unroll
                for (int a = 0; a < 4; ++a)
                    #pragma unroll
                    for (int d = 0; d < 4; ++d) {
                        float v = 0.f;
                        #pragma unroll
                        for (int x = 0; x < 4; ++x)
                            v = fmaf(u16[a * 4 + x], cwv[x * 4 + d], v);
                        votes[a * 4 + d] = v;
                    }
                float qk = 0.f;
                #pragma unroll
                for (int j = 0; j < 16; ++j) qk = fmaf(votes[j], nvp[s][j], qk);
                qk *= 0.25f;                          // 1/sqrt(16)
                float e = __expf(fminf(fmaxf(qk, -30.f), 30.f));
                float sm = e;
                #pragma unroll
                for (int off = 1; off < 32; off <<= 1) sm += __shfl_xor(sm, off);
                float qv = e / sm;
                #pragma unroll
                for (int j = 0; j < 16; ++j) nvacc[s][j] = fmaf(qv, votes[j], nvacc[s][j]);
            }
            wq0 = nq0; wq1 = nq1;
        }
    }

    // reduce -> nv2 -> LN -> global  (wred aliases ulocH; barrier-separated)
    #pragma unroll
    for (int s = 0; s < 2; ++s)
        #pragma unroll
        for (int j = 0; j < 16; ++j)
            nvacc[s][j] += __shfl_xor(nvacc[s][j], 32);
    #pragma unroll
    for (int s = 0; s < 2; ++s) {
        __syncthreads();
        if (half0) {
            #pragma unroll
            for (int j = 0; j < 16; ++j) wred[wid * 544 + lane * 17 + j] = nvacc[s][j];
        }
        __syncthreads();
        for (int o = threadIdx.x; o < 512; o += 256) {
            int mm = o >> 4, j = o & 15;
            float sum = wred[0 * 544 + mm * 17 + j] + wred[1 * 544 + mm * 17 + j]
                      + wred[2 * 544 + mm * 17 + j] + wred[3 * 544 + mm * 17 + j];
            v1s[s][o] = sum;
        }
    }
    __syncthreads();
    if (threadIdx.x < 64) {
        int s = threadIdx.x >> 5, m = threadIdx.x & 31;
        int b = bb + s * 32;
        float v16[16], mu = 0.f;
        #pragma unroll
        for (int j = 0; j < 16; ++j) { v16[j] = v1s[s][m * 16 + j]; mu += v16[j]; }
        mu *= (1.f / 16.f);
        float var = 0.f;
        #pragma unroll
        for (int j = 0; j < 16; ++j) { float t = v16[j] - mu; var += t * t; }
        var *= (1.f / 16.f);
        float rs = rsqrtf(var + EPSLN);
        float o16[16];
        #pragma unroll
        for (int j = 0; j < 16; ++j) o16[j] = (v16[j] - mu) * rs * g[j] + bt[j];
        float4* dst = (float4*)(vout + (((b * 32 + m) * 7 + h) * 7 + w) * 16);
        dst[0] = make_float4(o16[0],  o16[1],  o16[2],  o16[3]);
        dst[1] = make_float4(o16[4],  o16[5],  o16[6],  o16[7]);
        dst[2] = make_float4(o16[8],  o16[9],  o16[10], o16[11]);
        dst[3] = make_float4(o16[12], o16[13], o16[14], o16[15]);
    }
}

// ===================== fc step1 + LN2: v2 -> p =====================
__global__ __launch_bounds__(256) void k_fc1(const float* __restrict__ fin,
                                             const float* __restrict__ fwp,
                                             const float* __restrict__ g,
                                             const float* __restrict__ bt,
                                             float* __restrict__ p) {
    int b = blockIdx.x / 10, m = blockIdx.x % 10;
    const float* fb = fin + b * 1568 * 16;
    const float* wb = fwp + m * 1568 * 16;
    float acc[16];
    #pragma unroll
    for (int j = 0; j < 16; ++j) acc[j] = 0.f;

    for (int n = threadIdx.x; n < 1568; n += 256) {
        const float4* u4 = (const float4*)(fb + n * 16);
        const float4* w4 = (const float4*)(wb + n * 16);
        float u16[16], w16[16];
        #pragma unroll
        for (int f = 0; f < 4; ++f) {
            float4 a = u4[f], bq = w4[f];
            u16[f * 4 + 0] = a.x;  u16[f * 4 + 1] = a.y;
            u16[f * 4 + 2] = a.z;  u16[f * 4 + 3] = a.w;
            w16[f * 4 + 0] = bq.x; w16[f * 4 + 1] = bq.y;
            w16[f * 4 + 2] = bq.z; w16[f * 4 + 3] = bq.w;
        }
        #pragma unroll
        for (int a = 0; a < 4; ++a)
            #pragma unroll
            for (int d = 0; d < 4; ++d) {
                float s = acc[a * 4 + d];
                #pragma unroll
                for (int x = 0; x < 4; ++x)
                    s = fmaf(u16[a * 4 + x], w16[x * 4 + d], s);
                acc[a * 4 + d] = s;
            }
    }
    #pragma unroll
    for (int j = 0; j < 16; ++j)
        #pragma unroll
        for (int off = 1; off < 64; off <<= 1)
            acc[j] += __shfl_xor(acc[j], off);

    __shared__ float red[4][16];
    int wid = threadIdx.x >> 6, ln = threadIdx.x & 63;
    if (ln == 0) {
        #pragma unroll
        for (int j = 0; j < 16; ++j) red[wid][j] = acc[j];
    }
    __syncthreads();
    if (threadIdx.x < 16) {
        int j = threadIdx.x;
        float s = (red[0][j] + red[1][j] + red[2][j] + red[3][j]) * 0.1f;
        float mu = s;
        #pragma unroll
        for (int off = 1; off < 16; off <<= 1) mu += __shfl_xor(mu, off);
        mu *= (1.f / 16.f);
        float t = s - mu;
        float var = t * t;
        #pragma unroll
        for (int off = 1; off < 16; off <<= 1) var += __shfl_xor(var, off);
        var *= (1.f / 16.f);
        float rs = rsqrtf(var + EPSLN);
        p[(b * 10 + m) * 16 + j] = t * rs * g[j] + bt[j];
    }
}

// ===================== fc routing + LN2 (1024 threads): v2,p -> out =====================
__global__ __launch_bounds__(1024) void k_fc2(const float* __restrict__ fin,
                                              const float* __restrict__ fw,
                                              const float* __restrict__ p,
                                              const float* __restrict__ g,
                                              const float* __restrict__ bt,
                                              float* __restrict__ out) {
    int b = blockIdx.x;
    int ad    = threadIdx.x & 15;
    int grpid = threadIdx.x >> 4;   // 0..63
    int a = ad >> 2, d = ad & 3;

    float pv[10];
    #pragma unroll
    for (int m = 0; m < 10; ++m) pv[m] = p[(b * 10 + m) * 16 + ad];

    float acc[10];
    #pragma unroll
    for (int m = 0; m < 10; ++m) acc[m] = 0.f;

    const float* fb = fin + b * 1568 * 16;
    for (int n = grpid; n < 1568; n += 64) {
        float4 u4 = *(const float4*)(fb + n * 16 + a * 4);
        const float* wb = fw + n * 160 + d * 10;
        float votes[10];
        #pragma unroll
        for (int m = 0; m < 10; ++m)
            votes[m] = u4.x * wb[m] + u4.y * wb[40 + m] +
                       u4.z * wb[80 + m] + u4.w * wb[120 + m];
        float qk[10];
        #pragma unroll
        for (int m = 0; m < 10; ++m) {
            float t = votes[m] * pv[m];
            #pragma unroll
            for (int off = 1; off < 16; off <<= 1) t += __shfl_xor(t, off);
            qk[m] = t * 0.25f;
        }
        float mx = qk[0];
        #pragma unroll
        for (int m = 1; m < 10; ++m) mx = fmaxf(mx, qk[m]);
        float e[10], s = 0.f;
        #pragma unroll
        for (int m = 0; m < 10; ++m) { e[m] = __expf(qk[m] - mx); s += e[m]; }
        float inv = 1.f / s;
        #pragma unroll
        for (int m = 0; m < 10; ++m) acc[m] = fmaf(e[m] * inv, votes[m], acc[m]);
    }

    __shared__ float red[64][16][10];   // 40 KB
    #pragma unroll
    for (int m = 0; m < 10; ++m) red[grpid][ad][m] = acc[m];
    __syncthreads();

    if (threadIdx.x < 160) {
        int m = threadIdx.x / 16, j = threadIdx.x % 16;
        float s = 0.f;
        for (int gg = 0; gg < 64; ++gg) s += red[gg][j][m];
        float mu = s;
        #pragma unroll
        for (int off = 1; off < 16; off <<= 1) mu += __shfl_xor(mu, off);
        mu *= (1.f / 16.f);
        float t = s - mu;
        float var = t * t;
        #pragma unroll
        for (int off = 1; off < 16; off <<= 1) var += __shfl_xor(var, off);
        var *= (1.f / 16.f);
        float rs = rsqrtf(var + EPSLN);
        out[(b * 10 + m) * 16 + j] = t * rs * g[j] + bt[j];
    }
}

// ============================ launch ============================
extern "C" void kernel_launch(void* const* d_in, const int* in_sizes, int n_in,
                              void* d_out, int out_size, void* d_ws, size_t ws_size,
                              hipStream_t stream) {
    const float* x    = (const float*)d_in[0];
    const float* bbw  = (const float*)d_in[1];
    const float* bbb  = (const float*)d_in[2];
    const float* pcw  = (const float*)d_in[3];
    const float* ln0g = (const float*)d_in[4];
    const float* ln0b = (const float*)d_in[5];
    const float* cwt  = (const float*)d_in[6];
    const float* ln1g = (const float*)d_in[7];
    const float* ln1b = (const float*)d_in[8];
    const float* fw   = (const float*)d_in[9];
    const float* ln2g = (const float*)d_in[10];
    const float* ln2b = (const float*)d_in[11];
    float* outp = (float*)d_out;

    // Workspace layout (f32 units) -- verified R11
    float* ws = (float*)d_ws;
    __bf16* c2p  = (__bf16*)ws;                 // [0,          4,734,976)
    __bf16* wbT  = (__bf16*)(ws + 4734976);     // [4,734,976,  5,029,888)
    float*  bwT  = ws + 5029888;                // [5,029,888,  5,033,344)
    float*  val  = ws + 5033344;                // [5,033,344, 13,421,952)
    float*  v2   = ws + 13421952;               // [13,421,952, 15,027,584)
    float*  fwp  = ws + 15027584;               // [15,027,584, 15,278,464)
    float*  p    = ws + 15278464;               // [15,278,464, 15,288,704)
    __bf16* cw2  = (__bf16*)(ws + 15288704);    // [15,288,704, 15,362,432)
    __bf16* cwB  = (__bf16*)(ws + 15362432);    // [15,362,432, 15,436,160)
    float*  nv1g = ws + 15436160;               // [15,436,160, 17,041,792)

    hipMemsetAsync(c2p, 0, (size_t)9469952 * 2, stream);
    k_repack_all <<<4450, 256, 0, stream>>>(bbw, bwT, pcw, wbT, fw, fwp, cwt, cw2, cwB);
    k_conv1      <<<8192, 256, 0, stream>>>(x, bwT, bbb, c2p);
    k_conv2_mfma <<<1024, 256, 0, stream>>>(c2p, wbT, ln0g, ln0b, val);
    k_nv1_mfma   <<<196,  256, 0, stream>>>(val, cwB, nv1g);
    k_capsfused  <<<1568, 256, 0, stream>>>(val, cw2, nv1g, ln1g, ln1b, v2);
    k_fc1        <<<640, 256, 0, stream>>>(v2, fwp, ln2g, ln2b, p);
    k_fc2        <<<64, 1024, 0, stream>>>(v2, fw, p, ln2g, ln2b, outp);
}

// Round 13
// 320.631 us; speedup vs baseline: 1.7917x; 1.0431x over previous
//
#include <hip/hip_runtime.h>

// CapsTimeModel forward, round 13: capsfused VALU diet.
//   - uloc staged in f32 (no bf16 pack/unpack): R8-R11 counters show occupancy
//     is NOT LDS-bound (25-26% at both 31.2KB and 22.5KB), so bf16 staging was
//     a pure VALU tax (~16 cvt/site-item). LDS -> 40KB.
//   - softmax: single-sided overflow clamp, rcp instead of divide.
// All other kernels identical to R12 (passing, 334us).

#define EPSLN 1e-5f

typedef short  short8 __attribute__((ext_vector_type(8)));
typedef __bf16 bf16x8 __attribute__((ext_vector_type(8)));
typedef float  f32x4  __attribute__((ext_vector_type(4)));

union Frag { short8 s; bf16x8 b; };

__device__ __forceinline__ uint4 pack_bf16_8(float4 a, float4 b) {
    union { __bf16 h[8]; uint4 u; } r;
    r.h[0] = (__bf16)a.x; r.h[1] = (__bf16)a.y;
    r.h[2] = (__bf16)a.z; r.h[3] = (__bf16)a.w;
    r.h[4] = (__bf16)b.x; r.h[5] = (__bf16)b.y;
    r.h[6] = (__bf16)b.z; r.h[7] = (__bf16)b.w;
    return r.u;
}

// ==================== fused repacks (blockIdx-range dispatch) ====================
__global__ __launch_bounds__(256) void k_repack_all(
        const float* __restrict__ bw,  float* __restrict__ bwT,
        const float* __restrict__ pw,  __bf16* __restrict__ wbT,
        const float* __restrict__ fw,  float* __restrict__ fwp,
        const float* __restrict__ cw,  __bf16* __restrict__ cw2,
        __bf16* __restrict__ cwB) {
    int blk = blockIdx.x;
    if (blk < 2304) {                         // pcw -> wbT : 589824 exact
        int i = blk * 256 + threadIdx.x;
        int oc = i / 1152, r = i % 1152;
        int ic = r / 9, tap = r % 9;
        wbT[oc * 1152 + tap * 128 + ic] = (__bf16)pw[i];
    } else if (blk < 3284) {                  // fw -> fwp : 250880 exact
        int i = (blk - 2304) * 256 + threadIdx.x;
        int m = i % 10;
        int d = (i / 10) & 3;
        int x = (i / 40) & 3;
        int n = i / 160;
        fwp[(m * 1568 + n) * 16 + x * 4 + d] = fw[i];
    } else if (blk < 3860) {                  // cw -> cw2 : 147456 exact
        int i = (blk - 3284) * 256 + threadIdx.x;
        int m  = i & 31;
        int d  = (i >> 5) & 3;
        int x  = (i >> 7) & 3;
        int n  = (i >> 9) & 31;
        int kl = i >> 14;
        cw2[(((kl * 32 + n) * 32) + m) * 16 + x * 4 + d] = (__bf16)cw[i];
    } else if (blk < 4436) {                  // cw -> cwB : 147456 exact
        int i = (blk - 3860) * 256 + threadIdx.x;
        int m  = i & 31;
        int d  = (i >> 5) & 3;
        int x  = (i >> 7) & 3;
        int n  = (i >> 9) & 31;
        int kl = i >> 14;
        cwB[(m * 4 + d) * 1152 + (n * 9 + kl) * 4 + x] = (__bf16)cw[i];
    } else {                                  // bw -> bwT : 3456
        int i = (blk - 4436) * 256 + threadIdx.x;
        if (i < 3456) {
            int oc = i / 27, r = i % 27;
            bwT[r * 128 + oc] = bw[i];
        }
    }
}

// ==================== conv1: x -> c2p (NHWC bf16, padded), 4 oc/thread ====================
__global__ __launch_bounds__(256) void k_conv1(const float* __restrict__ x,
                                               const float* __restrict__ bwT,
                                               const float* __restrict__ bb,
                                               __bf16* __restrict__ c2p) {
    int gid = blockIdx.x * 256 + threadIdx.x;     // 2,097,152 (=64*32*32*32)
    int oc4 = gid & 31;
    int p   = gid >> 5;
    int w = p & 31, h = (p >> 5) & 31, b = p >> 10;
    const float* xb = x + b * 12288;
    float4 acc = *(const float4*)(bb + oc4 * 4);
    #pragma unroll
    for (int ky = 0; ky < 3; ++ky) {
        int ih = 2 * h + ky - 1;
        if ((unsigned)ih >= 64u) continue;
        #pragma unroll
        for (int kx = 0; kx < 3; ++kx) {
            int iw = 2 * w + kx - 1;
            if ((unsigned)iw >= 64u) continue;
            #pragma unroll
            for (int ic = 0; ic < 3; ++ic) {
                float in = xb[(ic * 64 + ih) * 64 + iw];
                float4 wv = *(const float4*)(bwT + (ic * 9 + ky * 3 + kx) * 128 + oc4 * 4);
                acc.x = fmaf(in, wv.x, acc.x);
                acc.y = fmaf(in, wv.y, acc.y);
                acc.z = fmaf(in, wv.z, acc.z);
                acc.w = fmaf(in, wv.w, acc.w);
            }
        }
    }
    union { __bf16 h4[4]; unsigned long long ull; } r;
    r.h4[0] = (__bf16)fmaxf(acc.x, 0.f);
    r.h4[1] = (__bf16)fmaxf(acc.y, 0.f);
    r.h4[2] = (__bf16)fmaxf(acc.z, 0.f);
    r.h4[3] = (__bf16)fmaxf(acc.w, 0.f);
    *(unsigned long long*)(c2p + ((b * 34 + h + 1) * 34 + (w + 1)) * 128 + oc4 * 4) = r.ull;
}

// ==================== conv2: pipelined MFMA GEMM + fused LN0 -> val ====================
__global__ __launch_bounds__(256) void k_conv2_mfma(const __bf16* __restrict__ c2p,
                                                    const __bf16* __restrict__ wbT,
                                                    const float* __restrict__ g,
                                                    const float* __restrict__ bt,
                                                    float* __restrict__ val) {
    __shared__ unsigned short sA[128 * 32];
    __shared__ unsigned short sB[64 * 32];

    const int t = threadIdx.x;
    const int mblk = blockIdx.x >> 3, nblk = blockIdx.x & 7;
    const int pbase = mblk * 128, ocbase = nblk * 64;
    const int b = pbase >> 8;

    const int r0 = t >> 2, r1 = r0 + 64;
    const int kc8 = (t & 3) * 8;
    const int oh0 = ((pbase + r0) >> 4) & 15, ow0 = (pbase + r0) & 15;
    const int oh1 = ((pbase + r1) >> 4) & 15, ow1 = (pbase + r1) & 15;

    const unsigned short* cb = (const unsigned short*)c2p + (size_t)b * 147968;
    const unsigned short* ws = (const unsigned short*)wbT
                               + (ocbase + (t >> 2)) * 1152 + kc8;

    const int lane = t & 63, wid = t >> 6;
    const int lo = lane & 15, hi = lane >> 4;

    f32x4 acc[2][4];
    #pragma unroll
    for (int fr = 0; fr < 2; ++fr)
        #pragma unroll
        for (int fc = 0; fc < 4; ++fc)
            acc[fr][fc] = (f32x4){0.f, 0.f, 0.f, 0.f};

    {
        uint4 a0 = *(const uint4*)(cb + ((2 * oh0) * 34 + 2 * ow0) * 128 + kc8);
        uint4 a1 = *(const uint4*)(cb + ((2 * oh1) * 34 + 2 * ow1) * 128 + kc8);
        uint4 b0 = *(const uint4*)(ws);
        *(uint4*)&sA[(unsigned)t * 8]         = a0;
        *(uint4*)&sA[((unsigned)t + 256) * 8] = a1;
        *(uint4*)&sB[(unsigned)t * 8]         = b0;
        __syncthreads();
    }

    for (int ks = 0; ks < 36; ++ks) {
        uint4 a0, a1, b0;
        const bool pre = (ks + 1) < 36;
        if (pre) {
            int ksn = ks + 1;
            int tap = ksn / 4, ic0 = (ksn % 4) * 32;
            int ty = tap / 3, tx = tap % 3;
            a0 = *(const uint4*)(cb + ((2 * oh0 + ty) * 34 + (2 * ow0 + tx)) * 128
                                    + ic0 + kc8);
            a1 = *(const uint4*)(cb + ((2 * oh1 + ty) * 34 + (2 * ow1 + tx)) * 128
                                    + ic0 + kc8);
            b0 = *(const uint4*)(ws + ksn * 32);
        }
        Frag af0, af1, bf[4];
        af0.s = *(const short8*)&sA[(wid * 32 + lo) * 32 + hi * 8];
        af1.s = *(const short8*)&sA[(wid * 32 + 16 + lo) * 32 + hi * 8];
        #pragma unroll
        for (int fc = 0; fc < 4; ++fc)
            bf[fc].s = *(const short8*)&sB[(fc * 16 + lo) * 32 + hi * 8];
        #pragma unroll
        for (int fc = 0; fc < 4; ++fc) {
            acc[0][fc] = __builtin_amdgcn_mfma_f32_16x16x32_bf16(
                af0.b, bf[fc].b, acc[0][fc], 0, 0, 0);
            acc[1][fc] = __builtin_amdgcn_mfma_f32_16x16x32_bf16(
                af1.b, bf[fc].b, acc[1][fc], 0, 0, 0);
        }
        __syncthreads();
        if (pre) {
            *(uint4*)&sA[(unsigned)t * 8]         = a0;
            *(uint4*)&sA[((unsigned)t + 256) * 8] = a1;
            *(uint4*)&sB[(unsigned)t * 8]         = b0;
        }
        __syncthreads();
    }

    const float gv = g[lo], bv = bt[lo];
    #pragma unroll
    for (int fr = 0; fr < 2; ++fr) {
        #pragma unroll
        for (int fc = 0; fc < 4; ++fc) {
            const int n = (ocbase >> 4) + fc;
            #pragma unroll
            for (int j = 0; j < 4; ++j) {
                float v = acc[fr][fc][j];
                float s1 = v, s2 = v * v;
                #pragma unroll
                for (int off = 1; off < 16; off <<= 1) {
                    s1 += __shfl_xor(s1, off);
                    s2 += __shfl_xor(s2, off);
                }
                float mu  = s1 * (1.f / 16.f);
                float var = s2 * (1.f / 16.f) - mu * mu;
                float rs  = rsqrtf(var + EPSLN);
                float o   = (v - mu) * rs * gv + bv;
                int p  = pbase + wid * 32 + fr * 16 + hi * 4 + j;
                int oh = (p >> 4) & 15, ow = p & 15;
                val[(((b * 32 + n) * 16 + oh) * 16 + ow) * 16 + lo] = o;
            }
        }
    }
}

// ==================== nv1 GEMM (pipelined): val x cwB -> nv1g ====================
__global__ __launch_bounds__(256) void k_nv1_mfma(const float* __restrict__ val,
                                                  const __bf16* __restrict__ cwB,
                                                  float* __restrict__ nv1g) {
    __shared__ unsigned short sA[128 * 32];
    __shared__ unsigned short sB[64 * 32];

    const int t = threadIdx.x;
    const int mblk = blockIdx.x >> 1, nblk = blockIdx.x & 1;
    const int pbase = mblk * 128, ocbase = nblk * 64;

    const float* vbase[2];
    #pragma unroll
    for (int u = 0; u < 2; ++u) {
        int r = pbase + (t >> 2) + u * 64;
        int site = r >> 2, a = r & 3;
        int b = site / 49, hw = site % 49;
        int h = hw / 7, w = hw % 7;
        vbase[u] = val + (size_t)b * 131072 + (2 * h) * 256 + (2 * w) * 16 + a * 4;
    }
    const unsigned short* wsrc = (const unsigned short*)cwB
                                 + (ocbase + (t >> 2)) * 1152 + (t & 3) * 8;

    const int lane = t & 63, wid = t >> 6;
    const int lo = lane & 15, hi = lane >> 4;

    f32x4 acc[2][4];
    #pragma unroll
    for (int fr = 0; fr < 2; ++fr)
        #pragma unroll
        for (int fc = 0; fc < 4; ++fc)
            acc[fr][fc] = (f32x4){0.f, 0.f, 0.f, 0.f};

    auto itemoff = [](int i) {
        int n = i / 9, kl = i % 9;
        return n * 4096 + (kl / 3) * 256 + (kl % 3) * 16;
    };

    {
        int i0 = (t & 3) * 2;
        int o0 = itemoff(i0), o1 = itemoff(i0 + 1);
        uint4 a0 = pack_bf16_8(*(const float4*)(vbase[0] + o0),
                               *(const float4*)(vbase[0] + o1));
        uint4 a1 = pack_bf16_8(*(const float4*)(vbase[1] + o0),
                               *(const float4*)(vbase[1] + o1));
        uint4 b0 = *(const uint4*)(wsrc);
        *(uint4*)&sA[(unsigned)t * 8]         = a0;
        *(uint4*)&sA[((unsigned)t + 256) * 8] = a1;
        *(uint4*)&sB[(unsigned)t * 8]         = b0;
        __syncthreads();
    }

    for (int ks = 0; ks < 36; ++ks) {
        uint4 a0, a1, b0;
        const bool pre = (ks + 1) < 36;
        if (pre) {
            int i0 = (ks + 1) * 8 + (t & 3) * 2;
            int o0 = itemoff(i0), o1 = itemoff(i0 + 1);
            a0 = pack_bf16_8(*(const float4*)(vbase[0] + o0),
                             *(const float4*)(vbase[0] + o1));
            a1 = pack_bf16_8(*(const float4*)(vbase[1] + o0),
                             *(const float4*)(vbase[1] + o1));
            b0 = *(const uint4*)(wsrc + (ks + 1) * 32);
        }
        Frag af0, af1, bf[4];
        af0.s = *(const short8*)&sA[(wid * 32 + lo) * 32 + hi * 8];
        af1.s = *(const short8*)&sA[(wid * 32 + 16 + lo) * 32 + hi * 8];
        #pragma unroll
        for (int fc = 0; fc < 4; ++fc)
            bf[fc].s = *(const short8*)&sB[(fc * 16 + lo) * 32 + hi * 8];
        #pragma unroll
        for (int fc = 0; fc < 4; ++fc) {
            acc[0][fc] = __builtin_amdgcn_mfma_f32_16x16x32_bf16(
                af0.b, bf[fc].b, acc[0][fc], 0, 0, 0);
            acc[1][fc] = __builtin_amdgcn_mfma_f32_16x16x32_bf16(
                af1.b, bf[fc].b, acc[1][fc], 0, 0, 0);
        }
        __syncthreads();
        if (pre) {
            *(uint4*)&sA[(unsigned)t * 8]         = a0;
            *(uint4*)&sA[((unsigned)t + 256) * 8] = a1;
            *(uint4*)&sB[(unsigned)t * 8]         = b0;
        }
        __syncthreads();
    }

    #pragma unroll
    for (int fr = 0; fr < 2; ++fr)
        #pragma unroll
        for (int fc = 0; fc < 4; ++fc)
            #pragma unroll
            for (int j = 0; j < 4; ++j) {
                int row = pbase + wid * 32 + fr * 16 + hi * 4 + j;
                int col = ocbase + fc * 16 + lo;
                nv1g[row * 128 + col] = acc[fr][fc][j];
            }
}

// ===================== caps routing pass 2 + LN1 (pass 1 via k_nv1_mfma) =====================
// uloc in f32 (40KB LDS total) -- no bf16 pack/unpack on the u path.
__global__ __launch_bounds__(256) void k_capsfused(const float* __restrict__ val,
                                                   const __bf16* __restrict__ cw2,
                                                   const float* __restrict__ nv1g,
                                                   const float* __restrict__ g,
                                                   const float* __restrict__ bt,
                                                   float* __restrict__ vout) {
    int bb = blockIdx.x / 49;
    int hw = blockIdx.x % 49;
    int h = hw / 7, w = hw % 7;

    __shared__ float4 uloc4[2][1152];   // 36864 B; aliased by wred after loop
    __shared__ float  v1s[2][512];      //  4096 B  nv2 scratch
    float* wred = (float*)uloc4;        //  8704 B needed <= 36864

    // stage unfolded val (f32 direct) for both sites
    for (int t = threadIdx.x; t < 2304; t += 256) {
        int s  = t >= 1152;
        int tt = t - s * 1152;
        int f  = tt & 3;
        int kl = (tt >> 2) % 9;
        int n  = tt / 36;
        int k = kl / 3, l = kl % 3;
        int b = bb + s * 32;
        uloc4[s][tt] = *(const float4*)(val +
            (((b * 32 + n) * 16 + (2 * h + k)) * 16 + (2 * w + l)) * 16 + f * 4);
    }

    const int lane  = threadIdx.x & 31;          // m
    const int grpid = threadIdx.x >> 5;          // 0..7
    const int wid   = threadIdx.x >> 6;          // 0..3
    const bool half0 = (threadIdx.x & 32) == 0;

    // nvp from nv1 GEMM: /32 + lane-local LN
    float nvp[2][16];
    #pragma unroll
    for (int s = 0; s < 2; ++s) {
        int site = (bb + s * 32) * 49 + hw;
        #pragma unroll
        for (int a = 0; a < 4; ++a) {
            float4 q = *(const float4*)(nv1g + (site * 4 + a) * 128 + lane * 4);
            nvp[s][a * 4 + 0] = q.x * (1.f / 32.f);
            nvp[s][a * 4 + 1] = q.y * (1.f / 32.f);
            nvp[s][a * 4 + 2] = q.z * (1.f / 32.f);
            nvp[s][a * 4 + 3] = q.w * (1.f / 32.f);
        }
        float mu = 0.f;
        #pragma unroll
        for (int j = 0; j < 16; ++j) mu += nvp[s][j];
        mu *= (1.f / 16.f);
        float var = 0.f;
        #pragma unroll
        for (int j = 0; j < 16; ++j) { float d = nvp[s][j] - mu; var += d * d; }
        var *= (1.f / 16.f);
        float rs = rsqrtf(var + EPSLN);
        #pragma unroll
        for (int j = 0; j < 16; ++j)
            nvp[s][j] = (nvp[s][j] - mu) * rs * g[j] + bt[j];
    }

    float nvacc[2][16];
    #pragma unroll
    for (int s = 0; s < 2; ++s)
        #pragma unroll
        for (int j = 0; j < 16; ++j) nvacc[s][j] = 0.f;

    __syncthreads();

    // ---------------- pass 2: routed ----------------
    {
        uint4 wq0, wq1;
        {
            int n = grpid / 9, kl = grpid % 9;
            const uint4* wb = (const uint4*)(cw2 + (((kl * 32 + n) * 32) + lane) * 16);
            wq0 = wb[0]; wq1 = wb[1];
        }
        for (int it = grpid; it < 288; it += 8) {
            int nit = it + 8;
            uint4 nq0 = wq0, nq1 = wq1;
            if (nit < 288) {
                int n = nit / 9, kl = nit % 9;
                const uint4* wb = (const uint4*)(cw2 + (((kl * 32 + n) * 32) + lane) * 16);
                nq0 = wb[0]; nq1 = wb[1];
            }
            float cwv[16];
            {
                union { uint4 u; __bf16 hh[8]; } qa, qb;
                qa.u = wq0; qb.u = wq1;
                #pragma unroll
                for (int j = 0; j < 8; ++j) {
                    cwv[j] = (float)qa.hh[j]; cwv[8 + j] = (float)qb.hh[j];
                }
            }
            #pragma unroll
            for (int s = 0; s < 2; ++s) {
                float u16[16];
                #pragma unroll
                for (int f = 0; f < 4; ++f) {
                    float4 t4 = uloc4[s][it * 4 + f];
                    u16[f * 4 + 0] = t4.x; u16[f * 4 + 1] = t4.y;
                    u16[f * 4 + 2] = t4.z; u16[f * 4 + 3] = t4.w;
                }
                float votes[16];
                #pragma unroll
                for (int a = 0; a < 4; ++a)
                    #pragma unroll
                    for (int d = 0; d < 4; ++d) {
                        float v = 0.f;
                        #pragma unroll
                        for (int x = 0; x < 4; ++x)
                            v = fmaf(u16[a * 4 + x], cwv[x * 4 + d], v);
                        votes[a * 4 + d] = v;
                    }
                float qk = 0.f;
                #pragma unroll
                for (int j = 0; j < 16; ++j) qk = fmaf(votes[j], nvp[s][j], qk);
                qk *= 0.25f;                          // 1/sqrt(16)
                float e = __expf(fminf(qk, 60.f));    // overflow guard only
                float sm = e;
                #pragma unroll
                for (int off = 1; off < 32; off <<= 1) sm += __shfl_xor(sm, off);
                float qv = e * __builtin_amdgcn_rcpf(sm);
                #pragma unroll
                for (int j = 0; j < 16; ++j) nvacc[s][j] = fmaf(qv, votes[j], nvacc[s][j]);
            }
            wq0 = nq0; wq1 = nq1;
        }
    }

    // reduce -> nv2 -> LN -> global  (wred aliases uloc4; barrier-separated)
    #pragma unroll
    for (int s = 0; s < 2; ++s)
        #pragma unroll
        for (int j = 0; j < 16; ++j)
            nvacc[s][j] += __shfl_xor(nvacc[s][j], 32);
    #pragma unroll
    for (int s = 0; s < 2; ++s) {
        __syncthreads();
        if (half0) {
            #pragma unroll
            for (int j = 0; j < 16; ++j) wred[wid * 544 + lane * 17 + j] = nvacc[s][j];
        }
        __syncthreads();
        for (int o = threadIdx.x; o < 512; o += 256) {
            int mm = o >> 4, j = o & 15;
            float sum = wred[0 * 544 + mm * 17 + j] + wred[1 * 544 + mm * 17 + j]
                      + wred[2 * 544 + mm * 17 + j] + wred[3 * 544 + mm * 17 + j];
            v1s[s][o] = sum;
        }
    }
    __syncthreads();
    if (threadIdx.x < 64) {
        int s = threadIdx.x >> 5, m = threadIdx.x & 31;
        int b = bb + s * 32;
        float v16[16], mu = 0.f;
        #pragma unroll
        for (int j = 0; j < 16; ++j) { v16[j] = v1s[s][m * 16 + j]; mu += v16[j]; }
        mu *= (1.f / 16.f);
        float var = 0.f;
        #pragma unroll
        for (int j = 0; j < 16; ++j) { float t = v16[j] - mu; var += t * t; }
        var *= (1.f / 16.f);
        float rs = rsqrtf(var + EPSLN);
        float o16[16];
        #pragma unroll
        for (int j = 0; j < 16; ++j) o16[j] = (v16[j] - mu) * rs * g[j] + bt[j];
        float4* dst = (float4*)(vout + (((b * 32 + m) * 7 + h) * 7 + w) * 16);
        dst[0] = make_float4(o16[0],  o16[1],  o16[2],  o16[3]);
        dst[1] = make_float4(o16[4],  o16[5],  o16[6],  o16[7]);
        dst[2] = make_float4(o16[8],  o16[9],  o16[10], o16[11]);
        dst[3] = make_float4(o16[12], o16[13], o16[14], o16[15]);
    }
}

// ===================== fc step1 + LN2: v2 -> p =====================
__global__ __launch_bounds__(256) void k_fc1(const float* __restrict__ fin,
                                             const float* __restrict__ fwp,
                                             const float* __restrict__ g,
                                             const float* __restrict__ bt,
                                             float* __restrict__ p) {
    int b = blockIdx.x / 10, m = blockIdx.x % 10;
    const float* fb = fin + b * 1568 * 16;
    const float* wb = fwp + m * 1568 * 16;
    float acc[16];
    #pragma unroll
    for (int j = 0; j < 16; ++j) acc[j] = 0.f;

    for (int n = threadIdx.x; n < 1568; n += 256) {
        const float4* u4 = (const float4*)(fb + n * 16);
        const float4* w4 = (const float4*)(wb + n * 16);
        float u16[16], w16[16];
        #pragma unroll
        for (int f = 0; f < 4; ++f) {
            float4 a = u4[f], bq = w4[f];
            u16[f * 4 + 0] = a.x;  u16[f * 4 + 1] = a.y;
            u16[f * 4 + 2] = a.z;  u16[f * 4 + 3] = a.w;
            w16[f * 4 + 0] = bq.x; w16[f * 4 + 1] = bq.y;
            w16[f * 4 + 2] = bq.z; w16[f * 4 + 3] = bq.w;
        }
        #pragma unroll
        for (int a = 0; a < 4; ++a)
            #pragma unroll
            for (int d = 0; d < 4; ++d) {
                float s = acc[a * 4 + d];
                #pragma unroll
                for (int x = 0; x < 4; ++x)
                    s = fmaf(u16[a * 4 + x], w16[x * 4 + d], s);
                acc[a * 4 + d] = s;
            }
    }
    #pragma unroll
    for (int j = 0; j < 16; ++j)
        #pragma unroll
        for (int off = 1; off < 64; off <<= 1)
            acc[j] += __shfl_xor(acc[j], off);

    __shared__ float red[4][16];
    int wid = threadIdx.x >> 6, ln = threadIdx.x & 63;
    if (ln == 0) {
        #pragma unroll
        for (int j = 0; j < 16; ++j) red[wid][j] = acc[j];
    }
    __syncthreads();
    if (threadIdx.x < 16) {
        int j = threadIdx.x;
        float s = (red[0][j] + red[1][j] + red[2][j] + red[3][j]) * 0.1f;
        float mu = s;
        #pragma unroll
        for (int off = 1; off < 16; off <<= 1) mu += __shfl_xor(mu, off);
        mu *= (1.f / 16.f);
        float t = s - mu;
        float var = t * t;
        #pragma unroll
        for (int off = 1; off < 16; off <<= 1) var += __shfl_xor(var, off);
        var *= (1.f / 16.f);
        float rs = rsqrtf(var + EPSLN);
        p[(b * 10 + m) * 16 + j] = t * rs * g[j] + bt[j];
    }
}

// ===================== fc routing + LN2 (1024 threads): v2,p -> out =====================
__global__ __launch_bounds__(1024) void k_fc2(const float* __restrict__ fin,
                                              const float* __restrict__ fw,
                                              const float* __restrict__ p,
                                              const float* __restrict__ g,
                                              const float* __restrict__ bt,
                                              float* __restrict__ out) {
    int b = blockIdx.x;
    int ad    = threadIdx.x & 15;
    int grpid = threadIdx.x >> 4;   // 0..63
    int a = ad >> 2, d = ad & 3;

    float pv[10];
    #pragma unroll
    for (int m = 0; m < 10; ++m) pv[m] = p[(b * 10 + m) * 16 + ad];

    float acc[10];
    #pragma unroll
    for (int m = 0; m < 10; ++m) acc[m] = 0.f;

    const float* fb = fin + b * 1568 * 16;
    for (int n = grpid; n < 1568; n += 64) {
        float4 u4 = *(const float4*)(fb + n * 16 + a * 4);
        const float* wb = fw + n * 160 + d * 10;
        float votes[10];
        #pragma unroll
        for (int m = 0; m < 10; ++m)
            votes[m] = u4.x * wb[m] + u4.y * wb[40 + m] +
                       u4.z * wb[80 + m] + u4.w * wb[120 + m];
        float qk[10];
        #pragma unroll
        for (int m = 0; m < 10; ++m) {
            float t = votes[m] * pv[m];
            #pragma unroll
            for (int off = 1; off < 16; off <<= 1) t += __shfl_xor(t, off);
            qk[m] = t * 0.25f;
        }
        float mx = qk[0];
        #pragma unroll
        for (int m = 1; m < 10; ++m) mx = fmaxf(mx, qk[m]);
        float e[10], s = 0.f;
        #pragma unroll
        for (int m = 0; m < 10; ++m) { e[m] = __expf(qk[m] - mx); s += e[m]; }
        float inv = 1.f / s;
        #pragma unroll
        for (int m = 0; m < 10; ++m) acc[m] = fmaf(e[m] * inv, votes[m], acc[m]);
    }

    __shared__ float red[64][16][10];   // 40 KB
    #pragma unroll
    for (int m = 0; m < 10; ++m) red[grpid][ad][m] = acc[m];
    __syncthreads();

    if (threadIdx.x < 160) {
        int m = threadIdx.x / 16, j = threadIdx.x % 16;
        float s = 0.f;
        for (int gg = 0; gg < 64; ++gg) s += red[gg][j][m];
        float mu = s;
        #pragma unroll
        for (int off = 1; off < 16; off <<= 1) mu += __shfl_xor(mu, off);
        mu *= (1.f / 16.f);
        float t = s - mu;
        float var = t * t;
        #pragma unroll
        for (int off = 1; off < 16; off <<= 1) var += __shfl_xor(var, off);
        var *= (1.f / 16.f);
        float rs = rsqrtf(var + EPSLN);
        out[(b * 10 + m) * 16 + j] = t * rs * g[j] + bt[j];
    }
}

// ============================ launch ============================
extern "C" void kernel_launch(void* const* d_in, const int* in_sizes, int n_in,
                              void* d_out, int out_size, void* d_ws, size_t ws_size,
                              hipStream_t stream) {
    const float* x    = (const float*)d_in[0];
    const float* bbw  = (const float*)d_in[1];
    const float* bbb  = (const float*)d_in[2];
    const float* pcw  = (const float*)d_in[3];
    const float* ln0g = (const float*)d_in[4];
    const float* ln0b = (const float*)d_in[5];
    const float* cwt  = (const float*)d_in[6];
    const float* ln1g = (const float*)d_in[7];
    const float* ln1b = (const float*)d_in[8];
    const float* fw   = (const float*)d_in[9];
    const float* ln2g = (const float*)d_in[10];
    const float* ln2b = (const float*)d_in[11];
    float* outp = (float*)d_out;

    // Workspace layout (f32 units) -- verified R11
    float* ws = (float*)d_ws;
    __bf16* c2p  = (__bf16*)ws;                 // [0,          4,734,976)
    __bf16* wbT  = (__bf16*)(ws + 4734976);     // [4,734,976,  5,029,888)
    float*  bwT  = ws + 5029888;                // [5,029,888,  5,033,344)
    float*  val  = ws + 5033344;                // [5,033,344, 13,421,952)
    float*  v2   = ws + 13421952;               // [13,421,952, 15,027,584)
    float*  fwp  = ws + 15027584;               // [15,027,584, 15,278,464)
    float*  p    = ws + 15278464;               // [15,278,464, 15,288,704)
    __bf16* cw2  = (__bf16*)(ws + 15288704);    // [15,288,704, 15,362,432)
    __bf16* cwB  = (__bf16*)(ws + 15362432);    // [15,362,432, 15,436,160)
    float*  nv1g = ws + 15436160;               // [15,436,160, 17,041,792)

    hipMemsetAsync(c2p, 0, (size_t)9469952 * 2, stream);
    k_repack_all <<<4450, 256, 0, stream>>>(bbw, bwT, pcw, wbT, fw, fwp, cwt, cw2, cwB);
    k_conv1      <<<8192, 256, 0, stream>>>(x, bwT, bbb, c2p);
    k_conv2_mfma <<<1024, 256, 0, stream>>>(c2p, wbT, ln0g, ln0b, val);
    k_nv1_mfma   <<<196,  256, 0, stream>>>(val, cwB, nv1g);
    k_capsfused  <<<1568, 256, 0, stream>>>(val, cw2, nv1g, ln1g, ln1b, v2);
    k_fc1        <<<640, 256, 0, stream>>>(v2, fwp, ln2g, ln2b, p);
    k_fc2        <<<64, 1024, 0, stream>>>(v2, fw, p, ln2g, ln2b, outp);
}